// Round 5
// baseline (4707.971 us; speedup 1.0000x reference)
//
#include <hip/hip_runtime.h>
#include <cstdint>

#define NN 2000     // nodes
#define NP 2048     // padded nodes
#define TT 12
#define BBATCH 32
#define HH 64
#define EE 10

typedef _Float16 f16;
typedef _Float16 f16x8 __attribute__((ext_vector_type(8)));
typedef float f32x4 __attribute__((ext_vector_type(4)));
typedef unsigned int u32;

// async global->LDS, 16B per lane; lds must be wave-uniform base (HW adds lane*16)
__device__ __forceinline__ void gld_lds16(const void* g, void* lds) {
    __builtin_amdgcn_global_load_lds(
        (const __attribute__((address_space(1))) u32*)(const void*)g,
        (__attribute__((address_space(3))) u32*)(void*)lds, 16, 0, 0);
}

// ---------------- supports: A = softmax(relu(emb @ emb^T)), fp16, padded [NP][NP] ----------------
__global__ __launch_bounds__(256) void k_supports(const float* __restrict__ emb, f16* __restrict__ A2) {
    int n = blockIdx.x;
    int tid = threadIdx.x;
    if (n >= NN) {
        for (int m = tid; m < NP; m += 256) A2[(size_t)n * NP + m] = (f16)0.f;
        return;
    }
    __shared__ float red[4];
    float en[EE];
#pragma unroll
    for (int e = 0; e < EE; e++) en[e] = emb[n * EE + e];
    float g[8];
    float mx = 0.f;
#pragma unroll
    for (int i = 0; i < 8; i++) {
        int m = tid + 256 * i;
        float v = 0.f;
        if (m < NN) {
            float a = 0.f;
#pragma unroll
            for (int e = 0; e < EE; e++) a += en[e] * emb[m * EE + e];
            v = fmaxf(a, 0.f);
            mx = fmaxf(mx, v);
        }
        g[i] = v;
    }
#pragma unroll
    for (int d = 32; d; d >>= 1) mx = fmaxf(mx, __shfl_xor(mx, d));
    if ((tid & 63) == 0) red[tid >> 6] = mx;
    __syncthreads();
    mx = fmaxf(fmaxf(red[0], red[1]), fmaxf(red[2], red[3]));
    float s = 0.f;
#pragma unroll
    for (int i = 0; i < 8; i++) {
        int m = tid + 256 * i;
        if (m < NN) { g[i] = __expf(g[i] - mx); s += g[i]; }
    }
#pragma unroll
    for (int d = 32; d; d >>= 1) s += __shfl_xor(s, d);
    __syncthreads();
    if ((tid & 63) == 0) red[tid >> 6] = s;
    __syncthreads();
    s = red[0] + red[1] + red[2] + red[3];
    float inv = 1.f / s;
#pragma unroll
    for (int i = 0; i < 8; i++) {
        int m = tid + 256 * i;
        A2[(size_t)n * NP + m] = (m < NN) ? (f16)(g[i] * inv) : (f16)0.f;
    }
}

// ---------------- wgen: W^T[n][o][r] = sum_e emb[n,e] * wpool[e,k(r),c(r),o]  (fp16) ----------------
template <int DIN, int O>
__global__ __launch_bounds__(256) void k_wgen(const float* __restrict__ emb,
                                              const float* __restrict__ wpool,
                                              f16* __restrict__ WT) {
    constexpr int DPAD = (DIN == 66) ? 80 : 128;
    constexpr int R = 2 * DPAD;
    int n0 = blockIdx.x * 4;
    int r = threadIdx.x;
    if (r >= R) return;
    int k = (r >= DPAD) ? 1 : 0;
    int c = r - k * DPAD;
    bool valid = (c < DIN);
    float en[4][EE];
#pragma unroll
    for (int j = 0; j < 4; j++)
#pragma unroll
        for (int e = 0; e < EE; e++) en[j][e] = emb[(n0 + j) * EE + e];
    const float* wp = wpool + ((size_t)(k * DIN + (valid ? c : 0))) * O;
    for (int o = 0; o < O; o += 4) {
        float4 a[4] = {};
        if (valid) {
#pragma unroll
            for (int e = 0; e < EE; e++) {
                float4 w4 = *(const float4*)(wp + (size_t)e * 2 * DIN * O + o);
#pragma unroll
                for (int j = 0; j < 4; j++) {
                    a[j].x += en[j][e] * w4.x; a[j].y += en[j][e] * w4.y;
                    a[j].z += en[j][e] * w4.z; a[j].w += en[j][e] * w4.w;
                }
            }
        }
#pragma unroll
        for (int j = 0; j < 4; j++) {
            f16* outp = WT + ((size_t)(n0 + j) * O + o) * R + r;
            outp[0] = (f16)a[j].x; outp[(size_t)R] = (f16)a[j].y;
            outp[(size_t)2 * R] = (f16)a[j].z; outp[(size_t)3 * R] = (f16)a[j].w;
        }
    }
}

// ---------------- pack layer0 x_t into xs0/us0 x-part (row-major only) ----------------
__global__ __launch_bounds__(256) void k_pack(const float* __restrict__ x, int t,
                                              f16* __restrict__ xs, f16* __restrict__ us) {
    int idx = blockIdx.x * 256 + threadIdx.x;  // over b*2*NN, n fastest
    if (idx >= BBATCH * 2 * NN) return;
    int n = idx % NN;
    int bd = idx / NN;
    int d = bd & 1, b = bd >> 1;
    float v = x[(((size_t)b * TT + t) * NN + n) * 2 + d];
    f16 h = (f16)v;
    xs[(size_t)n * (BBATCH * 66) + b * 66 + d] = h;
    us[(size_t)n * (BBATCH * 66) + b * 66 + d] = h;
}

// ---------------- tiled transpose: out[j][m] = in[m][j], in [NP-ish rows][W], clamp m>=NN to 0 ----
template <int W>
__global__ __launch_bounds__(256) void k_tr(const f16* __restrict__ in, f16* __restrict__ out) {
    __shared__ f16 t[64][72];
    int bx = blockIdx.x, by = blockIdx.y;
    int tid = threadIdx.x;
    int ml = tid >> 2, q = tid & 3;
    int m = by * 64 + ml;
    f16x8 a, b2;
#pragma unroll
    for (int i = 0; i < 8; i++) { a[i] = (f16)0.f; b2[i] = (f16)0.f; }
    if (m < NN) {
        const f16* src = in + (size_t)m * W + bx * 64 + q * 16;
        a = *(const f16x8*)src;
        b2 = *(const f16x8*)(src + 8);
    }
    *(f16x8*)&t[ml][q * 16] = a;
    *(f16x8*)&t[ml][q * 16 + 8] = b2;
    __syncthreads();
    int jl = tid >> 2;
    f16x8 r0, r1;
#pragma unroll
    for (int i = 0; i < 8; i++) r0[i] = t[q * 16 + i][jl];
#pragma unroll
    for (int i = 0; i < 8; i++) r1[i] = t[q * 16 + 8 + i][jl];
    f16* dst = out + (size_t)(bx * 64 + jl) * NP + by * 64 + q * 16;
    *(f16x8*)dst = r0;
    *(f16x8*)(dst + 8) = r1;
}

// ---------------- aggregation GEMM: C[2048][J] = A2[2048][2048] @ XT'[...][2048]^T --------------
// m97-structure: 128x128 tile, BK=64, 4 waves (2x2), per-wave 64x64 output, acc[4][4].
// row map: C col j -> XT row j' = (j/64)*ST + OFF + j%64 (identity when ST=64, OFF=0)
template <int ST, int OFF>
__global__ __launch_bounds__(256) void k_gemm(const f16* __restrict__ A2, const f16* __restrict__ XT,
                                              f16* __restrict__ C, int J) {
    __shared__ __align__(16) f16 at[128 * 64];
    __shared__ __align__(16) f16 xt[128 * 64];
    int tj = blockIdx.x * 128;
    int tm = blockIdx.y * 128;
    int jb = (tj >> 6) * ST + OFF;
    int tid = threadIdx.x;
    int w = tid >> 6, l = tid & 63;
    int lr = l & 15, lg = l >> 4;
    int wr = w >> 1, wc = w & 1;
    f32x4 acc[4][4];
#pragma unroll
    for (int mt = 0; mt < 4; mt++)
#pragma unroll
        for (int nt = 0; nt < 4; nt++) acc[mt][nt] = (f32x4){0.f, 0.f, 0.f, 0.f};

    for (int k0 = 0; k0 < 2048; k0 += 64) {
        // stage A tile: 16KB (wave w covers LDS elems [w*2048, w*2048+2048))
#pragma unroll
        for (int i = 0; i < 4; i++) {
            int e = w * 2048 + i * 512 + l * 8;
            int row = e >> 6, s = (e >> 3) & 7;
            const f16* src = A2 + (size_t)(tm + row) * 2048 + k0 + ((s ^ (row & 7)) << 3);
            gld_lds16(src, &at[w * 2048 + i * 512]);
        }
        // stage X tile: 16KB, with affine 64-block row map
#pragma unroll
        for (int i = 0; i < 4; i++) {
            int e = w * 2048 + i * 512 + l * 8;
            int row = e >> 6, s = (e >> 3) & 7;
            int jp = jb + (row >> 6) * ST + (row & 63);
            const f16* src = XT + (size_t)jp * 2048 + k0 + ((s ^ (row & 7)) << 3);
            gld_lds16(src, &xt[w * 2048 + i * 512]);
        }
        __syncthreads();
#pragma unroll
        for (int kk = 0; kk < 2; kk++) {
            int s = kk * 4 + lg;
            f16x8 av[4], bv[4];
#pragma unroll
            for (int mt = 0; mt < 4; mt++) {
                int row = wr * 64 + mt * 16 + lr;
                av[mt] = *(const f16x8*)&at[row * 64 + ((s ^ (row & 7)) << 3)];
            }
#pragma unroll
            for (int nt = 0; nt < 4; nt++) {
                int row = wc * 64 + nt * 16 + lr;
                bv[nt] = *(const f16x8*)&xt[row * 64 + ((s ^ (row & 7)) << 3)];
            }
#pragma unroll
            for (int mt = 0; mt < 4; mt++)
#pragma unroll
                for (int nt = 0; nt < 4; nt++)
                    acc[mt][nt] = __builtin_amdgcn_mfma_f32_16x16x32_f16(av[mt], bv[nt], acc[mt][nt], 0, 0, 0);
        }
        __syncthreads();
    }
#pragma unroll
    for (int mt = 0; mt < 4; mt++)
#pragma unroll
        for (int nt = 0; nt < 4; nt++)
#pragma unroll
            for (int q = 0; q < 4; q++) {
                int row = tm + wr * 64 + mt * 16 + lg * 4 + q;
                int col = tj + wc * 64 + nt * 16 + lr;
                C[(size_t)row * J + col] = (f16)acc[mt][nt][q];
            }
}

// ---------------- fused per-node gate: zr = sigmoid(xg @ W + b); u = z*h; store u (row-major), r --
template <int L>
__global__ __launch_bounds__(256) void k_gate(const f16* __restrict__ xs_rm, const f16* __restrict__ agg,
                                              const f16* __restrict__ WT, const float* __restrict__ bpool,
                                              const float* __restrict__ emb, const float* __restrict__ hbuf,
                                              f16* __restrict__ us_rm, float* __restrict__ rbuf) {
    constexpr int DIN = L ? 128 : 66, CIN = L ? 64 : 2, DPAD = L ? 128 : 80;
    constexpr int AGS = L ? 4096 : 2176;  // agg row stride (padded for L0)
    constexpr int R = 2 * DPAD, RPAD = R + 8, KCH = R / 32;
    constexpr int O = 128;
    int n = blockIdx.x;
    int tid = threadIdx.x, w = tid >> 6, l = tid & 63;
    int lr = l & 15, lg = l >> 4;
    __shared__ __align__(16) f16 xg[32 * RPAD];

    f16x8 wf[KCH][2];
    const f16* wbase = WT + (size_t)n * O * R;
#pragma unroll
    for (int kk = 0; kk < KCH; kk++)
#pragma unroll
        for (int nt = 0; nt < 2; nt++) {
            int o = w * 32 + nt * 16 + lr;
            wf[kk][nt] = *(const f16x8*)(wbase + (size_t)o * R + kk * 32 + lg * 8);
        }
    for (int i = tid; i < 32 * RPAD / 8; i += 256) *(float4*)&xg[i * 8] = (float4){0.f, 0.f, 0.f, 0.f};
    __syncthreads();
    if (L == 0) {
        for (int e = tid; e < 32 * DIN; e += 256) {
            int b = e / DIN, c = e % DIN;
            xg[b * RPAD + c] = xs_rm[(size_t)n * 32 * DIN + e];
            xg[b * RPAD + DPAD + c] = agg[(size_t)n * AGS + e];
        }
    } else {
        for (int e8 = tid; e8 < 32 * DIN / 8; e8 += 256) {
            int b = e8 >> 4, c8 = e8 & 15;
            *(f16x8*)&xg[b * RPAD + c8 * 8] = *(const f16x8*)&xs_rm[(size_t)n * 32 * DIN + e8 * 8];
            *(f16x8*)&xg[b * RPAD + DPAD + c8 * 8] = *(const f16x8*)&agg[(size_t)n * AGS + e8 * 8];
        }
    }
    __syncthreads();

    f32x4 acc[2][2];
#pragma unroll
    for (int mt = 0; mt < 2; mt++)
#pragma unroll
        for (int nt = 0; nt < 2; nt++) acc[mt][nt] = (f32x4){0.f, 0.f, 0.f, 0.f};
#pragma unroll
    for (int kk = 0; kk < KCH; kk++) {
        f16x8 av[2];
#pragma unroll
        for (int mt = 0; mt < 2; mt++)
            av[mt] = *(const f16x8*)&xg[(mt * 16 + lr) * RPAD + kk * 32 + lg * 8];
#pragma unroll
        for (int mt = 0; mt < 2; mt++)
#pragma unroll
            for (int nt = 0; nt < 2; nt++)
                acc[mt][nt] = __builtin_amdgcn_mfma_f32_16x16x32_f16(av[mt], wf[kk][nt], acc[mt][nt], 0, 0, 0);
    }
    float bias[2];
#pragma unroll
    for (int nt = 0; nt < 2; nt++) {
        int o = w * 32 + nt * 16 + lr;
        float bs = 0.f;
#pragma unroll
        for (int e = 0; e < EE; e++) bs += emb[n * EE + e] * bpool[e * 2 * HH + o];
        bias[nt] = bs;
    }
#pragma unroll
    for (int mt = 0; mt < 2; mt++)
#pragma unroll
        for (int nt = 0; nt < 2; nt++)
#pragma unroll
            for (int q = 0; q < 4; q++) {
                int o = w * 32 + nt * 16 + lr;
                int b = mt * 16 + lg * 4 + q;
                float v = acc[mt][nt][q] + bias[nt];
                float sg = 1.f / (1.f + __expf(-v));
                if (o < HH) {  // z half
                    float u = sg * hbuf[((size_t)n * 32 + b) * HH + o];
                    us_rm[(size_t)n * 32 * DIN + b * DIN + CIN + o] = (f16)u;
                } else {       // r half
                    rbuf[((size_t)n * 32 + b) * HH + (o - HH)] = sg;
                }
            }
}

// ---------------- fused per-node update: hc = tanh(xg @ W + b); h' = r*h + (1-r)*hc ---------------
template <int L>
__global__ __launch_bounds__(256) void k_upd(const f16* __restrict__ us_rm, const f16* __restrict__ agg,
                                             const f16* __restrict__ uagg, const f16* __restrict__ WT,
                                             const float* __restrict__ bpool, const float* __restrict__ emb,
                                             float* hbuf, const float* __restrict__ rbuf,
                                             f16* xs_self, f16* xsn, f16* usn,
                                             float* dout, int t) {
    constexpr int DIN = L ? 128 : 66, CIN = L ? 64 : 2, DPAD = L ? 128 : 80;
    constexpr int AGS = L ? 4096 : 2176;  // agg row stride (padded for L0)
    constexpr int R = 2 * DPAD, RPAD = R + 8, KCH = R / 32;
    constexpr int O = 64;
    int n = blockIdx.x;
    int tid = threadIdx.x, w = tid >> 6, l = tid & 63;
    int lr = l & 15, lg = l >> 4;
    __shared__ __align__(16) f16 xg[32 * RPAD];

    f16x8 wf[KCH];
    const f16* wbase = WT + (size_t)n * O * R;
    int o = w * 16 + lr;
#pragma unroll
    for (int kk = 0; kk < KCH; kk++)
        wf[kk] = *(const f16x8*)(wbase + (size_t)o * R + kk * 32 + lg * 8);

    for (int i = tid; i < 32 * RPAD / 8; i += 256) *(float4*)&xg[i * 8] = (float4){0.f, 0.f, 0.f, 0.f};
    __syncthreads();
    if (L == 0) {
        for (int e = tid; e < 32 * DIN; e += 256) {
            int b = e / DIN, c = e % DIN;
            xg[b * RPAD + c] = us_rm[(size_t)n * 32 * DIN + e];
            f16 v = (c < CIN) ? agg[(size_t)n * AGS + b * DIN + c]
                              : uagg[(size_t)n * 32 * HH + b * HH + (c - CIN)];
            xg[b * RPAD + DPAD + c] = v;
        }
    } else {
        for (int e8 = tid; e8 < 32 * DIN / 8; e8 += 256) {
            int b = e8 >> 4, c8 = e8 & 15;
            *(f16x8*)&xg[b * RPAD + c8 * 8] = *(const f16x8*)&us_rm[(size_t)n * 32 * DIN + e8 * 8];
            f16x8 v = (c8 < 8) ? *(const f16x8*)&agg[(size_t)n * AGS + b * DIN + c8 * 8]
                               : *(const f16x8*)&uagg[(size_t)n * 32 * HH + b * HH + (c8 - 8) * 8];
            *(f16x8*)&xg[b * RPAD + DPAD + c8 * 8] = v;
        }
    }
    __syncthreads();

    f32x4 acc[2];
#pragma unroll
    for (int mt = 0; mt < 2; mt++) acc[mt] = (f32x4){0.f, 0.f, 0.f, 0.f};
#pragma unroll
    for (int kk = 0; kk < KCH; kk++) {
        f16x8 av[2];
#pragma unroll
        for (int mt = 0; mt < 2; mt++)
            av[mt] = *(const f16x8*)&xg[(mt * 16 + lr) * RPAD + kk * 32 + lg * 8];
#pragma unroll
        for (int mt = 0; mt < 2; mt++)
            acc[mt] = __builtin_amdgcn_mfma_f32_16x16x32_f16(av[mt], wf[kk], acc[mt], 0, 0, 0);
    }
    float bias = 0.f;
#pragma unroll
    for (int e = 0; e < EE; e++) bias += emb[n * EE + e] * bpool[e * HH + o];
#pragma unroll
    for (int mt = 0; mt < 2; mt++)
#pragma unroll
        for (int q = 0; q < 4; q++) {
            int b = mt * 16 + lg * 4 + q;
            float v = acc[mt][q] + bias;
            float ex = __expf(2.f * v);
            float hc = 1.f - 2.f / (ex + 1.f);  // tanh
            size_t hidx = ((size_t)n * 32 + b) * HH + o;
            float r = rbuf[hidx], h = hbuf[hidx];
            float hn = r * h + (1.f - r) * hc;
            hbuf[hidx] = hn;
            f16 hh = (f16)hn;
            xs_self[(size_t)n * 32 * DIN + b * DIN + CIN + o] = hh;
            if (L == 0) {
                xsn[(size_t)n * 32 * 128 + b * 128 + o] = hh;
                usn[(size_t)n * 32 * 128 + b * 128 + o] = hh;
            } else {
                dout[(((size_t)b * TT + t) * NN + n) * HH + o] = hn;
                if (t == TT - 1)
                    dout[(size_t)BBATCH * TT * NN * HH + ((size_t)b * NN + n) * HH + o] = hn;
            }
        }
}

extern "C" void kernel_launch(void* const* d_in, const int* in_sizes, int n_in,
                              void* d_out, int out_size, void* d_ws, size_t ws_size,
                              hipStream_t stream) {
    (void)in_sizes; (void)n_in; (void)out_size; (void)ws_size;
    const float* x   = (const float*)d_in[0];
    const float* emb = (const float*)d_in[1];
    const float* gw0 = (const float*)d_in[2];
    const float* gb0 = (const float*)d_in[3];
    const float* uw0 = (const float*)d_in[4];
    const float* ub0 = (const float*)d_in[5];
    const float* gw1 = (const float*)d_in[6];
    const float* gb1 = (const float*)d_in[7];
    const float* uw1 = (const float*)d_in[8];
    const float* ub1 = (const float*)d_in[9];
    float* out = (float*)d_out;

    char* p = (char*)d_ws;
    auto alloc = [&](size_t bytes) { char* r = p; p += (bytes + 255) & ~(size_t)255; return r; };
    f16* A2    = (f16*)alloc((size_t)NP * NP * 2);
    f16* Wg0   = (f16*)alloc((size_t)NN * 128 * 160 * 2);
    f16* Wu0   = (f16*)alloc((size_t)NN * 64 * 160 * 2);
    f16* Wg1   = (f16*)alloc((size_t)NN * 128 * 256 * 2);
    f16* Wu1   = (f16*)alloc((size_t)NN * 64 * 256 * 2);
    f16* xs0   = (f16*)alloc((size_t)NN * 32 * 66 * 2);
    f16* xsT0  = (f16*)alloc((size_t)2176 * NP * 2);   // 2176 rows: padded for 128-wide j-tiles
    f16* agg0  = (f16*)alloc((size_t)NP * 2176 * 2);   // stride 2176
    f16* us0   = (f16*)alloc((size_t)NN * 32 * 66 * 2);
    f16* usT0  = (f16*)alloc((size_t)2176 * NP * 2);
    f16* uagg0 = (f16*)alloc((size_t)NP * 2048 * 2);
    f16* xs1   = (f16*)alloc((size_t)NN * 32 * 128 * 2);
    f16* xsT1  = (f16*)alloc((size_t)4096 * NP * 2);
    f16* agg1  = (f16*)alloc((size_t)NP * 4096 * 2);
    f16* us1   = (f16*)alloc((size_t)NN * 32 * 128 * 2);
    f16* usT1  = (f16*)alloc((size_t)4096 * NP * 2);
    f16* uagg1 = (f16*)alloc((size_t)NP * 2048 * 2);
    float* h0  = (float*)alloc((size_t)NN * 32 * 64 * 4);
    float* r0  = (float*)alloc((size_t)NN * 32 * 64 * 4);
    float* h1  = (float*)alloc((size_t)NN * 32 * 64 * 4);
    float* r1  = (float*)alloc((size_t)NN * 32 * 64 * 4);

    // zero recurrent-state-bearing row-major buffers (h-parts must be 0 at t=0)
    hipMemsetAsync(xs0, 0, (size_t)NN * 32 * 66 * 2, stream);
    hipMemsetAsync(xs1, 0, (size_t)NN * 32 * 128 * 2, stream);
    hipMemsetAsync(h0, 0, (size_t)NN * 32 * 64 * 4, stream);
    hipMemsetAsync(h1, 0, (size_t)NN * 32 * 64 * 4, stream);

    k_supports<<<NP, 256, 0, stream>>>(emb, A2);
    k_wgen<66, 128><<<NN / 4, 256, 0, stream>>>(emb, gw0, Wg0);
    k_wgen<66, 64><<<NN / 4, 256, 0, stream>>>(emb, uw0, Wu0);
    k_wgen<128, 128><<<NN / 4, 256, 0, stream>>>(emb, gw1, Wg1);
    k_wgen<128, 64><<<NN / 4, 256, 0, stream>>>(emb, uw1, Wu1);

    for (int t = 0; t < TT; t++) {
        // ---- layer 0 ----
        k_pack<<<500, 256, 0, stream>>>(x, t, xs0, us0);
        k_tr<2112><<<dim3(33, 32), 256, 0, stream>>>(xs0, xsT0);
        k_gemm<64, 0><<<dim3(17, 16), 256, 0, stream>>>(A2, xsT0, agg0, 2176);
        k_gate<0><<<NN, 256, 0, stream>>>(xs0, agg0, Wg0, gb0, emb, h0, us0, r0);
        k_tr<2112><<<dim3(33, 32), 256, 0, stream>>>(us0, usT0);
        k_gemm<66, 2><<<dim3(16, 16), 256, 0, stream>>>(A2, usT0, uagg0, 2048);
        k_upd<0><<<NN, 256, 0, stream>>>(us0, agg0, uagg0, Wu0, ub0, emb, h0, r0,
                                         xs0, xs1, us1, nullptr, t);
        // ---- layer 1 ----
        k_tr<4096><<<dim3(64, 32), 256, 0, stream>>>(xs1, xsT1);
        k_gemm<64, 0><<<dim3(32, 16), 256, 0, stream>>>(A2, xsT1, agg1, 4096);
        k_gate<1><<<NN, 256, 0, stream>>>(xs1, agg1, Wg1, gb1, emb, h1, us1, r1);
        k_tr<4096><<<dim3(64, 32), 256, 0, stream>>>(us1, usT1);
        k_gemm<128, 64><<<dim3(16, 16), 256, 0, stream>>>(A2, usT1, uagg1, 2048);
        k_upd<1><<<NN, 256, 0, stream>>>(us1, agg1, uagg1, Wu1, ub1, emb, h1, r1,
                                         xs1, nullptr, nullptr, out, t);
    }
}

// Round 6
// 4410.787 us; speedup vs baseline: 1.0674x; 1.0674x over previous
//
#include <hip/hip_runtime.h>
#include <cstdint>

#define NN 2000     // nodes
#define NP 2048     // padded nodes
#define TT 12
#define BBATCH 32
#define HH 64
#define EE 10

typedef _Float16 f16;
typedef _Float16 f16x8 __attribute__((ext_vector_type(8)));
typedef float f32x4 __attribute__((ext_vector_type(4)));
typedef unsigned int u32;

// async global->LDS, 16B per lane; lds must be wave-uniform base (HW adds lane*16)
__device__ __forceinline__ void gld_lds16(const void* g, void* lds) {
    __builtin_amdgcn_global_load_lds(
        (const __attribute__((address_space(1))) u32*)(const void*)g,
        (__attribute__((address_space(3))) u32*)(void*)lds, 16, 0, 0);
}

// ---------------- supports: A = softmax(relu(emb @ emb^T)), fp16, padded [NP][NP] ----------------
__global__ __launch_bounds__(256) void k_supports(const float* __restrict__ emb, f16* __restrict__ A2) {
    int n = blockIdx.x;
    int tid = threadIdx.x;
    if (n >= NN) {
        for (int m = tid; m < NP; m += 256) A2[(size_t)n * NP + m] = (f16)0.f;
        return;
    }
    __shared__ float red[4];
    float en[EE];
#pragma unroll
    for (int e = 0; e < EE; e++) en[e] = emb[n * EE + e];
    float g[8];
    float mx = 0.f;
#pragma unroll
    for (int i = 0; i < 8; i++) {
        int m = tid + 256 * i;
        float v = 0.f;
        if (m < NN) {
            float a = 0.f;
#pragma unroll
            for (int e = 0; e < EE; e++) a += en[e] * emb[m * EE + e];
            v = fmaxf(a, 0.f);
            mx = fmaxf(mx, v);
        }
        g[i] = v;
    }
#pragma unroll
    for (int d = 32; d; d >>= 1) mx = fmaxf(mx, __shfl_xor(mx, d));
    if ((tid & 63) == 0) red[tid >> 6] = mx;
    __syncthreads();
    mx = fmaxf(fmaxf(red[0], red[1]), fmaxf(red[2], red[3]));
    float s = 0.f;
#pragma unroll
    for (int i = 0; i < 8; i++) {
        int m = tid + 256 * i;
        if (m < NN) { g[i] = __expf(g[i] - mx); s += g[i]; }
    }
#pragma unroll
    for (int d = 32; d; d >>= 1) s += __shfl_xor(s, d);
    __syncthreads();
    if ((tid & 63) == 0) red[tid >> 6] = s;
    __syncthreads();
    s = red[0] + red[1] + red[2] + red[3];
    float inv = 1.f / s;
#pragma unroll
    for (int i = 0; i < 8; i++) {
        int m = tid + 256 * i;
        A2[(size_t)n * NP + m] = (m < NN) ? (f16)(g[i] * inv) : (f16)0.f;
    }
}

// ---------------- wgen: W^T[n][o][r] = sum_e emb[n,e] * wpool[e,k(r),c(r),o]  (fp16) ----------------
template <int DIN, int O>
__global__ __launch_bounds__(256) void k_wgen(const float* __restrict__ emb,
                                              const float* __restrict__ wpool,
                                              f16* __restrict__ WT) {
    constexpr int DPAD = (DIN == 66) ? 80 : 128;
    constexpr int R = 2 * DPAD;
    int n0 = blockIdx.x * 4;
    int r = threadIdx.x;
    if (r >= R) return;
    int k = (r >= DPAD) ? 1 : 0;
    int c = r - k * DPAD;
    bool valid = (c < DIN);
    float en[4][EE];
#pragma unroll
    for (int j = 0; j < 4; j++)
#pragma unroll
        for (int e = 0; e < EE; e++) en[j][e] = emb[(n0 + j) * EE + e];
    const float* wp = wpool + ((size_t)(k * DIN + (valid ? c : 0))) * O;
    for (int o = 0; o < O; o += 4) {
        float4 a[4] = {};
        if (valid) {
#pragma unroll
            for (int e = 0; e < EE; e++) {
                float4 w4 = *(const float4*)(wp + (size_t)e * 2 * DIN * O + o);
#pragma unroll
                for (int j = 0; j < 4; j++) {
                    a[j].x += en[j][e] * w4.x; a[j].y += en[j][e] * w4.y;
                    a[j].z += en[j][e] * w4.z; a[j].w += en[j][e] * w4.w;
                }
            }
        }
#pragma unroll
        for (int j = 0; j < 4; j++) {
            f16* outp = WT + ((size_t)(n0 + j) * O + o) * R + r;
            outp[0] = (f16)a[j].x; outp[(size_t)R] = (f16)a[j].y;
            outp[(size_t)2 * R] = (f16)a[j].z; outp[(size_t)3 * R] = (f16)a[j].w;
        }
    }
}

// ---------------- pack layer0 x_t into xs0/us0 x-part (row-major only) ----------------
__global__ __launch_bounds__(256) void k_pack(const float* __restrict__ x, int t,
                                              f16* __restrict__ xs, f16* __restrict__ us) {
    int idx = blockIdx.x * 256 + threadIdx.x;  // over b*2*NN, n fastest
    if (idx >= BBATCH * 2 * NN) return;
    int n = idx % NN;
    int bd = idx / NN;
    int d = bd & 1, b = bd >> 1;
    float v = x[(((size_t)b * TT + t) * NN + n) * 2 + d];
    f16 h = (f16)v;
    xs[(size_t)n * (BBATCH * 66) + b * 66 + d] = h;
    us[(size_t)n * (BBATCH * 66) + b * 66 + d] = h;
}

// ---------------- tiled transpose: out[j][m] = in[m][j], in [NP-ish rows][W], clamp m>=NN to 0 ----
template <int W>
__global__ __launch_bounds__(256) void k_tr(const f16* __restrict__ in, f16* __restrict__ out) {
    __shared__ f16 t[64][72];
    int bx = blockIdx.x, by = blockIdx.y;
    int tid = threadIdx.x;
    int ml = tid >> 2, q = tid & 3;
    int m = by * 64 + ml;
    f16x8 a, b2;
#pragma unroll
    for (int i = 0; i < 8; i++) { a[i] = (f16)0.f; b2[i] = (f16)0.f; }
    if (m < NN) {
        const f16* src = in + (size_t)m * W + bx * 64 + q * 16;
        a = *(const f16x8*)src;
        b2 = *(const f16x8*)(src + 8);
    }
    *(f16x8*)&t[ml][q * 16] = a;
    *(f16x8*)&t[ml][q * 16 + 8] = b2;
    __syncthreads();
    int jl = tid >> 2;
    f16x8 r0, r1;
#pragma unroll
    for (int i = 0; i < 8; i++) r0[i] = t[q * 16 + i][jl];
#pragma unroll
    for (int i = 0; i < 8; i++) r1[i] = t[q * 16 + 8 + i][jl];
    f16* dst = out + (size_t)(bx * 64 + jl) * NP + by * 64 + q * 16;
    *(f16x8*)dst = r0;
    *(f16x8*)(dst + 8) = r1;
}

// ---------------- aggregation GEMM: C[2048][J] = A2[2048][2048] @ XT'[...][2048]^T --------------
// 128x64 tile, BK=64, 4 waves, double-buffered LDS with prefetch (1 barrier/K-step),
// XCD-aware block swizzle (requires nwg%8==0, gridDim.y==16).
// row map: C col j -> XT row j' = (j/64)*ST + OFF + j%64 (identity when ST=64, OFF=0)
template <int ST, int OFF>
__global__ __launch_bounds__(256) void k_gemm(const f16* __restrict__ A2, const f16* __restrict__ XT,
                                              f16* __restrict__ C, int J) {
    __shared__ __align__(16) f16 at[2][128 * 64];
    __shared__ __align__(16) f16 xt[2][64 * 64];
    int id = blockIdx.x + gridDim.x * blockIdx.y;
    int q = (gridDim.x * 16) >> 3;              // blocks per XCD
    int sid = (id & 7) * q + (id >> 3);         // bijective XCD chunking
    int tj = (sid >> 4) * 64;                   // j-tile (y-fastest inside chunk)
    int tm = (sid & 15) * 128;                  // m-tile
    int rowbase = (tj >> 6) * ST + OFF;
    int tid = threadIdx.x;
    int w = tid >> 6, l = tid & 63;
    int lr = l & 15, lg = l >> 4;
    f32x4 acc[2][4];
#pragma unroll
    for (int mt = 0; mt < 2; mt++)
#pragma unroll
        for (int nt = 0; nt < 4; nt++) acc[mt][nt] = (f32x4){0.f, 0.f, 0.f, 0.f};

    auto stage = [&](int buf, int k0) {
        // A tile: 16KB (wave w covers LDS elems [w*2048, w*2048+2048))
#pragma unroll
        for (int i = 0; i < 4; i++) {
            int e = w * 2048 + i * 512 + l * 8;
            int row = e >> 6, s = (e >> 3) & 7;
            const f16* src = A2 + (size_t)(tm + row) * 2048 + k0 + ((s ^ (row & 7)) << 3);
            gld_lds16(src, &at[buf][w * 2048 + i * 512]);
        }
        // X tile: 8KB
#pragma unroll
        for (int i = 0; i < 2; i++) {
            int e = w * 1024 + i * 512 + l * 8;
            int row = e >> 6, s = (e >> 3) & 7;
            const f16* src = XT + (size_t)(rowbase + row) * 2048 + k0 + ((s ^ (row & 7)) << 3);
            gld_lds16(src, &xt[buf][w * 1024 + i * 512]);
        }
    };

    stage(0, 0);
    __syncthreads();                 // drains vmcnt(0): buf0 ready
    int cur = 0;
    for (int k0 = 0; k0 < 2048; k0 += 64) {
        if (k0 + 64 < 2048) stage(cur ^ 1, k0 + 64);   // prefetch next tile (overlaps MFMA below)
#pragma unroll
        for (int kk = 0; kk < 2; kk++) {
            int s = kk * 4 + lg;
            f16x8 av[2], bv[4];
#pragma unroll
            for (int mt = 0; mt < 2; mt++) {
                int row = w * 32 + mt * 16 + lr;
                av[mt] = *(const f16x8*)&at[cur][row * 64 + ((s ^ (row & 7)) << 3)];
            }
#pragma unroll
            for (int nt = 0; nt < 4; nt++) {
                int row = nt * 16 + lr;
                bv[nt] = *(const f16x8*)&xt[cur][row * 64 + ((s ^ (row & 7)) << 3)];
            }
#pragma unroll
            for (int mt = 0; mt < 2; mt++)
#pragma unroll
                for (int nt = 0; nt < 4; nt++)
                    acc[mt][nt] = __builtin_amdgcn_mfma_f32_16x16x32_f16(av[mt], bv[nt], acc[mt][nt], 0, 0, 0);
        }
        __syncthreads();             // one barrier/K-step: drains prefetch loads + LDS reads
        cur ^= 1;
    }
#pragma unroll
    for (int mt = 0; mt < 2; mt++)
#pragma unroll
        for (int nt = 0; nt < 4; nt++)
#pragma unroll
            for (int q2 = 0; q2 < 4; q2++) {
                int row = tm + w * 32 + mt * 16 + lg * 4 + q2;
                int col = tj + nt * 16 + lr;
                C[(size_t)row * J + col] = (f16)acc[mt][nt][q2];
            }
}

// ---------------- fused per-node gate: zr = sigmoid(xg @ W + b); u = z*h; store u (row-major), r --
template <int L>
__global__ __launch_bounds__(256) void k_gate(const f16* __restrict__ xs_rm, const f16* __restrict__ agg,
                                              const f16* __restrict__ WT, const float* __restrict__ bpool,
                                              const float* __restrict__ emb, const float* __restrict__ hbuf,
                                              f16* __restrict__ us_rm, float* __restrict__ rbuf) {
    constexpr int DIN = L ? 128 : 66, CIN = L ? 64 : 2, DPAD = L ? 128 : 80;
    constexpr int R = 2 * DPAD, RPAD = R + 8, KCH = R / 32;
    constexpr int O = 128;
    int n = blockIdx.x;
    int tid = threadIdx.x, w = tid >> 6, l = tid & 63;
    int lr = l & 15, lg = l >> 4;
    __shared__ __align__(16) f16 xg[32 * RPAD];

    f16x8 wf[KCH][2];
    const f16* wbase = WT + (size_t)n * O * R;
#pragma unroll
    for (int kk = 0; kk < KCH; kk++)
#pragma unroll
        for (int nt = 0; nt < 2; nt++) {
            int o = w * 32 + nt * 16 + lr;
            wf[kk][nt] = *(const f16x8*)(wbase + (size_t)o * R + kk * 32 + lg * 8);
        }
    for (int i = tid; i < 32 * RPAD / 8; i += 256) *(float4*)&xg[i * 8] = (float4){0.f, 0.f, 0.f, 0.f};
    __syncthreads();
    if (L == 0) {
        for (int e = tid; e < 32 * DIN; e += 256) {
            int b = e / DIN, c = e % DIN;
            xg[b * RPAD + c] = xs_rm[(size_t)n * 32 * DIN + e];
            xg[b * RPAD + DPAD + c] = agg[(size_t)n * 32 * DIN + e];
        }
    } else {
        for (int e8 = tid; e8 < 32 * DIN / 8; e8 += 256) {
            int b = e8 >> 4, c8 = e8 & 15;
            *(f16x8*)&xg[b * RPAD + c8 * 8] = *(const f16x8*)&xs_rm[(size_t)n * 32 * DIN + e8 * 8];
            *(f16x8*)&xg[b * RPAD + DPAD + c8 * 8] = *(const f16x8*)&agg[(size_t)n * 32 * DIN + e8 * 8];
        }
    }
    __syncthreads();

    f32x4 acc[2][2];
#pragma unroll
    for (int mt = 0; mt < 2; mt++)
#pragma unroll
        for (int nt = 0; nt < 2; nt++) acc[mt][nt] = (f32x4){0.f, 0.f, 0.f, 0.f};
#pragma unroll
    for (int kk = 0; kk < KCH; kk++) {
        f16x8 av[2];
#pragma unroll
        for (int mt = 0; mt < 2; mt++)
            av[mt] = *(const f16x8*)&xg[(mt * 16 + lr) * RPAD + kk * 32 + lg * 8];
#pragma unroll
        for (int mt = 0; mt < 2; mt++)
#pragma unroll
            for (int nt = 0; nt < 2; nt++)
                acc[mt][nt] = __builtin_amdgcn_mfma_f32_16x16x32_f16(av[mt], wf[kk][nt], acc[mt][nt], 0, 0, 0);
    }
    float bias[2];
#pragma unroll
    for (int nt = 0; nt < 2; nt++) {
        int o = w * 32 + nt * 16 + lr;
        float bs = 0.f;
#pragma unroll
        for (int e = 0; e < EE; e++) bs += emb[n * EE + e] * bpool[e * 2 * HH + o];
        bias[nt] = bs;
    }
#pragma unroll
    for (int mt = 0; mt < 2; mt++)
#pragma unroll
        for (int nt = 0; nt < 2; nt++)
#pragma unroll
            for (int q = 0; q < 4; q++) {
                int o = w * 32 + nt * 16 + lr;
                int b = mt * 16 + lg * 4 + q;
                float v = acc[mt][nt][q] + bias[nt];
                float sg = 1.f / (1.f + __expf(-v));
                if (o < HH) {  // z half
                    float u = sg * hbuf[((size_t)n * 32 + b) * HH + o];
                    us_rm[(size_t)n * 32 * DIN + b * DIN + CIN + o] = (f16)u;
                } else {       // r half
                    rbuf[((size_t)n * 32 + b) * HH + (o - HH)] = sg;
                }
            }
}

// ---------------- fused per-node update: hc = tanh(xg @ W + b); h' = r*h + (1-r)*hc ---------------
template <int L>
__global__ __launch_bounds__(256) void k_upd(const f16* __restrict__ us_rm, const f16* __restrict__ agg,
                                             const f16* __restrict__ uagg, const f16* __restrict__ WT,
                                             const float* __restrict__ bpool, const float* __restrict__ emb,
                                             float* hbuf, const float* __restrict__ rbuf,
                                             f16* xs_self, f16* xsn, f16* usn,
                                             float* dout, int t) {
    constexpr int DIN = L ? 128 : 66, CIN = L ? 64 : 2, DPAD = L ? 128 : 80;
    constexpr int R = 2 * DPAD, RPAD = R + 8, KCH = R / 32;
    constexpr int O = 64;
    int n = blockIdx.x;
    int tid = threadIdx.x, w = tid >> 6, l = tid & 63;
    int lr = l & 15, lg = l >> 4;
    __shared__ __align__(16) f16 xg[32 * RPAD];

    f16x8 wf[KCH];
    const f16* wbase = WT + (size_t)n * O * R;
    int o = w * 16 + lr;
#pragma unroll
    for (int kk = 0; kk < KCH; kk++)
        wf[kk] = *(const f16x8*)(wbase + (size_t)o * R + kk * 32 + lg * 8);

    for (int i = tid; i < 32 * RPAD / 8; i += 256) *(float4*)&xg[i * 8] = (float4){0.f, 0.f, 0.f, 0.f};
    __syncthreads();
    if (L == 0) {
        for (int e = tid; e < 32 * DIN; e += 256) {
            int b = e / DIN, c = e % DIN;
            xg[b * RPAD + c] = us_rm[(size_t)n * 32 * DIN + e];
            f16 v = (c < CIN) ? agg[(size_t)n * 32 * DIN + b * DIN + c]
                              : uagg[(size_t)n * 32 * HH + b * HH + (c - CIN)];
            xg[b * RPAD + DPAD + c] = v;
        }
    } else {
        for (int e8 = tid; e8 < 32 * DIN / 8; e8 += 256) {
            int b = e8 >> 4, c8 = e8 & 15;
            *(f16x8*)&xg[b * RPAD + c8 * 8] = *(const f16x8*)&us_rm[(size_t)n * 32 * DIN + e8 * 8];
            f16x8 v = (c8 < 8) ? *(const f16x8*)&agg[(size_t)n * 32 * DIN + b * DIN + c8 * 8]
                               : *(const f16x8*)&uagg[(size_t)n * 32 * HH + b * HH + (c8 - 8) * 8];
            *(f16x8*)&xg[b * RPAD + DPAD + c8 * 8] = v;
        }
    }
    __syncthreads();

    f32x4 acc[2];
#pragma unroll
    for (int mt = 0; mt < 2; mt++) acc[mt] = (f32x4){0.f, 0.f, 0.f, 0.f};
#pragma unroll
    for (int kk = 0; kk < KCH; kk++) {
        f16x8 av[2];
#pragma unroll
        for (int mt = 0; mt < 2; mt++)
            av[mt] = *(const f16x8*)&xg[(mt * 16 + lr) * RPAD + kk * 32 + lg * 8];
#pragma unroll
        for (int mt = 0; mt < 2; mt++)
            acc[mt] = __builtin_amdgcn_mfma_f32_16x16x32_f16(av[mt], wf[kk], acc[mt], 0, 0, 0);
    }
    float bias = 0.f;
#pragma unroll
    for (int e = 0; e < EE; e++) bias += emb[n * EE + e] * bpool[e * HH + o];
#pragma unroll
    for (int mt = 0; mt < 2; mt++)
#pragma unroll
        for (int q = 0; q < 4; q++) {
            int b = mt * 16 + lg * 4 + q;
            float v = acc[mt][q] + bias;
            float ex = __expf(2.f * v);
            float hc = 1.f - 2.f / (ex + 1.f);  // tanh
            size_t hidx = ((size_t)n * 32 + b) * HH + o;
            float r = rbuf[hidx], h = hbuf[hidx];
            float hn = r * h + (1.f - r) * hc;
            hbuf[hidx] = hn;
            f16 hh = (f16)hn;
            xs_self[(size_t)n * 32 * DIN + b * DIN + CIN + o] = hh;
            if (L == 0) {
                xsn[(size_t)n * 32 * 128 + b * 128 + o] = hh;
                usn[(size_t)n * 32 * 128 + b * 128 + o] = hh;
            } else {
                dout[(((size_t)b * TT + t) * NN + n) * HH + o] = hn;
                if (t == TT - 1)
                    dout[(size_t)BBATCH * TT * NN * HH + ((size_t)b * NN + n) * HH + o] = hn;
            }
        }
}

extern "C" void kernel_launch(void* const* d_in, const int* in_sizes, int n_in,
                              void* d_out, int out_size, void* d_ws, size_t ws_size,
                              hipStream_t stream) {
    (void)in_sizes; (void)n_in; (void)out_size; (void)ws_size;
    const float* x   = (const float*)d_in[0];
    const float* emb = (const float*)d_in[1];
    const float* gw0 = (const float*)d_in[2];
    const float* gb0 = (const float*)d_in[3];
    const float* uw0 = (const float*)d_in[4];
    const float* ub0 = (const float*)d_in[5];
    const float* gw1 = (const float*)d_in[6];
    const float* gb1 = (const float*)d_in[7];
    const float* uw1 = (const float*)d_in[8];
    const float* ub1 = (const float*)d_in[9];
    float* out = (float*)d_out;

    char* p = (char*)d_ws;
    auto alloc = [&](size_t bytes) { char* r = p; p += (bytes + 255) & ~(size_t)255; return r; };
    f16* A2    = (f16*)alloc((size_t)NP * NP * 2);
    f16* Wg0   = (f16*)alloc((size_t)NN * 128 * 160 * 2);
    f16* Wu0   = (f16*)alloc((size_t)NN * 64 * 160 * 2);
    f16* Wg1   = (f16*)alloc((size_t)NN * 128 * 256 * 2);
    f16* Wu1   = (f16*)alloc((size_t)NN * 64 * 256 * 2);
    f16* xs0   = (f16*)alloc((size_t)NN * 32 * 66 * 2);
    f16* xsT0  = (f16*)alloc((size_t)2112 * NP * 2);
    f16* agg0  = (f16*)alloc((size_t)NP * 2112 * 2);
    f16* us0   = (f16*)alloc((size_t)NN * 32 * 66 * 2);
    f16* usT0  = (f16*)alloc((size_t)2112 * NP * 2);
    f16* uagg0 = (f16*)alloc((size_t)NP * 2048 * 2);
    f16* xs1   = (f16*)alloc((size_t)NN * 32 * 128 * 2);
    f16* xsT1  = (f16*)alloc((size_t)4096 * NP * 2);
    f16* agg1  = (f16*)alloc((size_t)NP * 4096 * 2);
    f16* us1   = (f16*)alloc((size_t)NN * 32 * 128 * 2);
    f16* usT1  = (f16*)alloc((size_t)4096 * NP * 2);
    f16* uagg1 = (f16*)alloc((size_t)NP * 2048 * 2);
    float* h0  = (float*)alloc((size_t)NN * 32 * 64 * 4);
    float* r0  = (float*)alloc((size_t)NN * 32 * 64 * 4);
    float* h1  = (float*)alloc((size_t)NN * 32 * 64 * 4);
    float* r1  = (float*)alloc((size_t)NN * 32 * 64 * 4);

    // zero recurrent-state-bearing row-major buffers (h-parts must be 0 at t=0)
    hipMemsetAsync(xs0, 0, (size_t)NN * 32 * 66 * 2, stream);
    hipMemsetAsync(xs1, 0, (size_t)NN * 32 * 128 * 2, stream);
    hipMemsetAsync(h0, 0, (size_t)NN * 32 * 64 * 4, stream);
    hipMemsetAsync(h1, 0, (size_t)NN * 32 * 64 * 4, stream);

    k_supports<<<NP, 256, 0, stream>>>(emb, A2);
    k_wgen<66, 128><<<NN / 4, 256, 0, stream>>>(emb, gw0, Wg0);
    k_wgen<66, 64><<<NN / 4, 256, 0, stream>>>(emb, uw0, Wu0);
    k_wgen<128, 128><<<NN / 4, 256, 0, stream>>>(emb, gw1, Wg1);
    k_wgen<128, 64><<<NN / 4, 256, 0, stream>>>(emb, uw1, Wu1);

    for (int t = 0; t < TT; t++) {
        // ---- layer 0 ----
        k_pack<<<500, 256, 0, stream>>>(x, t, xs0, us0);
        k_tr<2112><<<dim3(33, 32), 256, 0, stream>>>(xs0, xsT0);
        k_gemm<64, 0><<<dim3(33, 16), 256, 0, stream>>>(A2, xsT0, agg0, 2112);
        k_gate<0><<<NN, 256, 0, stream>>>(xs0, agg0, Wg0, gb0, emb, h0, us0, r0);
        k_tr<2112><<<dim3(33, 32), 256, 0, stream>>>(us0, usT0);
        k_gemm<66, 2><<<dim3(32, 16), 256, 0, stream>>>(A2, usT0, uagg0, 2048);
        k_upd<0><<<NN, 256, 0, stream>>>(us0, agg0, uagg0, Wu0, ub0, emb, h0, r0,
                                         xs0, xs1, us1, nullptr, t);
        // ---- layer 1 ----
        k_tr<4096><<<dim3(64, 32), 256, 0, stream>>>(xs1, xsT1);
        k_gemm<64, 0><<<dim3(64, 16), 256, 0, stream>>>(A2, xsT1, agg1, 4096);
        k_gate<1><<<NN, 256, 0, stream>>>(xs1, agg1, Wg1, gb1, emb, h1, us1, r1);
        k_tr<4096><<<dim3(64, 32), 256, 0, stream>>>(us1, usT1);
        k_gemm<128, 64><<<dim3(32, 16), 256, 0, stream>>>(A2, usT1, uagg1, 2048);
        k_upd<1><<<NN, 256, 0, stream>>>(us1, agg1, uagg1, Wu1, ub1, emb, h1, r1,
                                         xs1, nullptr, nullptr, out, t);
    }
}

// Round 7
// 4035.770 us; speedup vs baseline: 1.1666x; 1.0929x over previous
//
#include <hip/hip_runtime.h>
#include <cstdint>

#define NN 2000     // nodes
#define NP 2048     // padded nodes
#define TT 12
#define BBATCH 32
#define HH 64
#define EE 10

typedef _Float16 f16;
typedef _Float16 f16x8 __attribute__((ext_vector_type(8)));
typedef float f32x4 __attribute__((ext_vector_type(4)));
typedef unsigned int u32;

// async global->LDS, 16B per lane; lds must be wave-uniform base (HW adds lane*16)
__device__ __forceinline__ void gld_lds16(const void* g, void* lds) {
    __builtin_amdgcn_global_load_lds(
        (const __attribute__((address_space(1))) u32*)(const void*)g,
        (__attribute__((address_space(3))) u32*)(void*)lds, 16, 0, 0);
}

// ---------------- supports: A = softmax(relu(emb @ emb^T)), fp16, padded [NP][NP] ----------------
__global__ __launch_bounds__(256) void k_supports(const float* __restrict__ emb, f16* __restrict__ A2) {
    int n = blockIdx.x;
    int tid = threadIdx.x;
    if (n >= NN) {
        for (int m = tid; m < NP; m += 256) A2[(size_t)n * NP + m] = (f16)0.f;
        return;
    }
    __shared__ float red[4];
    float en[EE];
#pragma unroll
    for (int e = 0; e < EE; e++) en[e] = emb[n * EE + e];
    float g[8];
    float mx = 0.f;
#pragma unroll
    for (int i = 0; i < 8; i++) {
        int m = tid + 256 * i;
        float v = 0.f;
        if (m < NN) {
            float a = 0.f;
#pragma unroll
            for (int e = 0; e < EE; e++) a += en[e] * emb[m * EE + e];
            v = fmaxf(a, 0.f);
            mx = fmaxf(mx, v);
        }
        g[i] = v;
    }
#pragma unroll
    for (int d = 32; d; d >>= 1) mx = fmaxf(mx, __shfl_xor(mx, d));
    if ((tid & 63) == 0) red[tid >> 6] = mx;
    __syncthreads();
    mx = fmaxf(fmaxf(red[0], red[1]), fmaxf(red[2], red[3]));
    float s = 0.f;
#pragma unroll
    for (int i = 0; i < 8; i++) {
        int m = tid + 256 * i;
        if (m < NN) { g[i] = __expf(g[i] - mx); s += g[i]; }
    }
#pragma unroll
    for (int d = 32; d; d >>= 1) s += __shfl_xor(s, d);
    __syncthreads();
    if ((tid & 63) == 0) red[tid >> 6] = s;
    __syncthreads();
    s = red[0] + red[1] + red[2] + red[3];
    float inv = 1.f / s;
#pragma unroll
    for (int i = 0; i < 8; i++) {
        int m = tid + 256 * i;
        A2[(size_t)n * NP + m] = (m < NN) ? (f16)(g[i] * inv) : (f16)0.f;
    }
}

// ---------------- wgen: W^T[n][o][r] = sum_e emb[n,e] * wpool[e,k(r),c(r),o]  (fp16) ----------------
template <int DIN, int O>
__global__ __launch_bounds__(256) void k_wgen(const float* __restrict__ emb,
                                              const float* __restrict__ wpool,
                                              f16* __restrict__ WT) {
    constexpr int DPAD = (DIN == 66) ? 80 : 128;
    constexpr int R = 2 * DPAD;
    int n0 = blockIdx.x * 4;
    int r = threadIdx.x;
    if (r >= R) return;
    int k = (r >= DPAD) ? 1 : 0;
    int c = r - k * DPAD;
    bool valid = (c < DIN);
    float en[4][EE];
#pragma unroll
    for (int j = 0; j < 4; j++)
#pragma unroll
        for (int e = 0; e < EE; e++) en[j][e] = emb[(n0 + j) * EE + e];
    const float* wp = wpool + ((size_t)(k * DIN + (valid ? c : 0))) * O;
    for (int o = 0; o < O; o += 4) {
        float4 a[4] = {};
        if (valid) {
#pragma unroll
            for (int e = 0; e < EE; e++) {
                float4 w4 = *(const float4*)(wp + (size_t)e * 2 * DIN * O + o);
#pragma unroll
                for (int j = 0; j < 4; j++) {
                    a[j].x += en[j][e] * w4.x; a[j].y += en[j][e] * w4.y;
                    a[j].z += en[j][e] * w4.z; a[j].w += en[j][e] * w4.w;
                }
            }
        }
#pragma unroll
        for (int j = 0; j < 4; j++) {
            f16* outp = WT + ((size_t)(n0 + j) * O + o) * R + r;
            outp[0] = (f16)a[j].x; outp[(size_t)R] = (f16)a[j].y;
            outp[(size_t)2 * R] = (f16)a[j].z; outp[(size_t)3 * R] = (f16)a[j].w;
        }
    }
}

// ---------------- xTall: [768][NP]; row r = t*64 + b*2 + d, col n = x[b][t][n][d] ----------------
__global__ __launch_bounds__(256) void k_xall(const float* __restrict__ x, f16* __restrict__ out) {
    int idx = blockIdx.x * 256 + threadIdx.x;
    if (idx >= 768 * NP) return;
    int r = idx >> 11, n = idx & (NP - 1);
    int t = r >> 6, rb = r & 63, b = rb >> 1, d = rb & 1;
    float v = (n < NN) ? x[(((size_t)b * TT + t) * NN + n) * 2 + d] : 0.f;
    out[idx] = (f16)v;
}

// ---------------- tiled transpose: out[(bx*TS+TO)*64+jl][m] = in[m][(bx*TS+TO)*64+jl] -------------
// in: [rows up to NN][W] f16; clamps m>=NN to 0.  TS/TO select a strided subset of 64-col tiles.
template <int W, int TS, int TO>
__global__ __launch_bounds__(256) void k_tr(const f16* __restrict__ in, f16* __restrict__ out) {
    __shared__ f16 t[64][72];
    int ebx = blockIdx.x * TS + TO, by = blockIdx.y;
    int tid = threadIdx.x;
    int ml = tid >> 2, q = tid & 3;
    int m = by * 64 + ml;
    f16x8 a, b2;
#pragma unroll
    for (int i = 0; i < 8; i++) { a[i] = (f16)0.f; b2[i] = (f16)0.f; }
    if (m < NN) {
        const f16* src = in + (size_t)m * W + ebx * 64 + q * 16;
        a = *(const f16x8*)src;
        b2 = *(const f16x8*)(src + 8);
    }
    *(f16x8*)&t[ml][q * 16] = a;
    *(f16x8*)&t[ml][q * 16 + 8] = b2;
    __syncthreads();
    int jl = tid >> 2;
    f16x8 r0, r1;
#pragma unroll
    for (int i = 0; i < 8; i++) r0[i] = t[q * 16 + i][jl];
#pragma unroll
    for (int i = 0; i < 8; i++) r1[i] = t[q * 16 + 8 + i][jl];
    f16* dst = out + (size_t)(ebx * 64 + jl) * NP + by * 64 + q * 16;
    *(f16x8*)dst = r0;
    *(f16x8*)(dst + 8) = r1;
}

// ---------------- aggregation GEMM: C[2048][J] = A2[2048][2048] @ XT'[...][2048]^T --------------
// 128x64 tile, BK=64, 4 waves, single-buffer (round-4 structure).
// row map: C col j -> XT row j' = (j/64)*ST + OFF + j%64
template <int ST, int OFF>
__global__ __launch_bounds__(256) void k_gemm(const f16* __restrict__ A2, const f16* __restrict__ XT,
                                              f16* __restrict__ C, int J) {
    __shared__ __align__(16) f16 at[128 * 64];
    __shared__ __align__(16) f16 xt[64 * 64];
    int tj = blockIdx.x * 64;
    int tm = blockIdx.y * 128;
    int rowbase = (tj >> 6) * ST + OFF;
    int tid = threadIdx.x;
    int w = tid >> 6, l = tid & 63;
    int lr = l & 15, lg = l >> 4;
    f32x4 acc[2][4];
#pragma unroll
    for (int mt = 0; mt < 2; mt++)
#pragma unroll
        for (int nt = 0; nt < 4; nt++) acc[mt][nt] = (f32x4){0.f, 0.f, 0.f, 0.f};

    for (int k0 = 0; k0 < 2048; k0 += 64) {
        // stage A tile: 16KB
#pragma unroll
        for (int i = 0; i < 4; i++) {
            int e = w * 2048 + i * 512 + l * 8;
            int row = e >> 6, s = (e >> 3) & 7;
            const f16* src = A2 + (size_t)(tm + row) * 2048 + k0 + ((s ^ (row & 7)) << 3);
            gld_lds16(src, &at[w * 2048 + i * 512]);
        }
        // stage X tile: 8KB
#pragma unroll
        for (int i = 0; i < 2; i++) {
            int e = w * 1024 + i * 512 + l * 8;
            int row = e >> 6, s = (e >> 3) & 7;
            const f16* src = XT + (size_t)(rowbase + row) * 2048 + k0 + ((s ^ (row & 7)) << 3);
            gld_lds16(src, &xt[w * 1024 + i * 512]);
        }
        __syncthreads();
#pragma unroll
        for (int kk = 0; kk < 2; kk++) {
            int s = kk * 4 + lg;
            f16x8 av[2], bv[4];
#pragma unroll
            for (int mt = 0; mt < 2; mt++) {
                int row = w * 32 + mt * 16 + lr;
                av[mt] = *(const f16x8*)&at[row * 64 + ((s ^ (row & 7)) << 3)];
            }
#pragma unroll
            for (int nt = 0; nt < 4; nt++) {
                int row = nt * 16 + lr;
                bv[nt] = *(const f16x8*)&xt[row * 64 + ((s ^ (row & 7)) << 3)];
            }
#pragma unroll
            for (int mt = 0; mt < 2; mt++)
#pragma unroll
                for (int nt = 0; nt < 4; nt++)
                    acc[mt][nt] = __builtin_amdgcn_mfma_f32_16x16x32_f16(av[mt], bv[nt], acc[mt][nt], 0, 0, 0);
        }
        __syncthreads();
    }
#pragma unroll
    for (int mt = 0; mt < 2; mt++)
#pragma unroll
        for (int nt = 0; nt < 4; nt++)
#pragma unroll
            for (int q = 0; q < 4; q++) {
                int row = tm + w * 32 + mt * 16 + lg * 4 + q;
                int col = tj + nt * 16 + lr;
                C[(size_t)row * J + col] = (f16)acc[mt][nt][q];
            }
}

// ---------------- gate0: zr = sigmoid([x_t,h0 | aggX,aggH0] @ Wg0 + b); us0 = z*h0; r0 ----------
__global__ __launch_bounds__(256) void k_gate0(const float* __restrict__ x, int t,
                                               const f16* __restrict__ h0rm, const f16* __restrict__ aggX,
                                               const f16* __restrict__ aggH0, const f16* __restrict__ WT,
                                               const float* __restrict__ bpool, const float* __restrict__ emb,
                                               const float* __restrict__ hbuf,
                                               f16* __restrict__ us_rm, float* __restrict__ rbuf) {
    constexpr int DIN = 66, DPAD = 80, R = 160, RPAD = 168, KCH = 5, O = 128;
    int n = blockIdx.x;
    int tid = threadIdx.x, w = tid >> 6, l = tid & 63;
    int lr = l & 15, lg = l >> 4;
    __shared__ __align__(16) f16 xg[32 * RPAD];

    f16x8 wf[KCH][2];
    const f16* wbase = WT + (size_t)n * O * R;
#pragma unroll
    for (int kk = 0; kk < KCH; kk++)
#pragma unroll
        for (int nt = 0; nt < 2; nt++) {
            int o = w * 32 + nt * 16 + lr;
            wf[kk][nt] = *(const f16x8*)(wbase + (size_t)o * R + kk * 32 + lg * 8);
        }
    for (int i = tid; i < 32 * RPAD / 8; i += 256) *(float4*)&xg[i * 8] = (float4){0.f, 0.f, 0.f, 0.f};
    __syncthreads();
    for (int e = tid; e < 32 * DIN; e += 256) {
        int b = e / DIN, c = e % DIN;
        f16 v1 = (c < 2) ? (f16)x[(((size_t)b * TT + t) * NN + n) * 2 + c]
                         : h0rm[(size_t)n * 2048 + b * 64 + (c - 2)];
        f16 v2 = (c < 2) ? aggX[(size_t)n * 768 + t * 64 + b * 2 + c]
                         : aggH0[(size_t)n * 2048 + b * 64 + (c - 2)];
        xg[b * RPAD + c] = v1;
        xg[b * RPAD + DPAD + c] = v2;
    }
    __syncthreads();

    f32x4 acc[2][2];
#pragma unroll
    for (int mt = 0; mt < 2; mt++)
#pragma unroll
        for (int nt = 0; nt < 2; nt++) acc[mt][nt] = (f32x4){0.f, 0.f, 0.f, 0.f};
#pragma unroll
    for (int kk = 0; kk < KCH; kk++) {
        f16x8 av[2];
#pragma unroll
        for (int mt = 0; mt < 2; mt++)
            av[mt] = *(const f16x8*)&xg[(mt * 16 + lr) * RPAD + kk * 32 + lg * 8];
#pragma unroll
        for (int mt = 0; mt < 2; mt++)
#pragma unroll
            for (int nt = 0; nt < 2; nt++)
                acc[mt][nt] = __builtin_amdgcn_mfma_f32_16x16x32_f16(av[mt], wf[kk][nt], acc[mt][nt], 0, 0, 0);
    }
#pragma unroll
    for (int mt = 0; mt < 2; mt++)
#pragma unroll
        for (int nt = 0; nt < 2; nt++) {
            int o = w * 32 + nt * 16 + lr;
            float bs = 0.f;
#pragma unroll
            for (int e = 0; e < EE; e++) bs += emb[n * EE + e] * bpool[e * 2 * HH + o];
#pragma unroll
            for (int q = 0; q < 4; q++) {
                int b = mt * 16 + lg * 4 + q;
                float v = acc[mt][nt][q] + bs;
                float sg = 1.f / (1.f + __expf(-v));
                if (o < HH) {
                    float u = sg * hbuf[((size_t)n * 32 + b) * HH + o];
                    us_rm[(size_t)n * 2048 + b * 64 + o] = (f16)u;
                } else {
                    rbuf[((size_t)n * 32 + b) * HH + (o - HH)] = sg;
                }
            }
        }
}

// ---------------- upd0: hc = tanh([x,z*h | aggX,uagg0] @ Wu0 + b); h0' -> h0rm, xs1, us1 ---------
__global__ __launch_bounds__(256) void k_upd0(const float* __restrict__ x, int t,
                                              const f16* __restrict__ us0, const f16* __restrict__ aggX,
                                              const f16* __restrict__ uagg, const f16* __restrict__ WT,
                                              const float* __restrict__ bpool, const float* __restrict__ emb,
                                              float* hbuf, const float* __restrict__ rbuf,
                                              f16* __restrict__ h0rm, f16* __restrict__ xs1,
                                              f16* __restrict__ us1) {
    constexpr int DIN = 66, DPAD = 80, R = 160, RPAD = 168, KCH = 5, O = 64;
    int n = blockIdx.x;
    int tid = threadIdx.x, w = tid >> 6, l = tid & 63;
    int lr = l & 15, lg = l >> 4;
    __shared__ __align__(16) f16 xg[32 * RPAD];

    f16x8 wf[KCH];
    const f16* wbase = WT + (size_t)n * O * R;
    int o = w * 16 + lr;
#pragma unroll
    for (int kk = 0; kk < KCH; kk++)
        wf[kk] = *(const f16x8*)(wbase + (size_t)o * R + kk * 32 + lg * 8);

    for (int i = tid; i < 32 * RPAD / 8; i += 256) *(float4*)&xg[i * 8] = (float4){0.f, 0.f, 0.f, 0.f};
    __syncthreads();
    for (int e = tid; e < 32 * DIN; e += 256) {
        int b = e / DIN, c = e % DIN;
        f16 v1 = (c < 2) ? (f16)x[(((size_t)b * TT + t) * NN + n) * 2 + c]
                         : us0[(size_t)n * 2048 + b * 64 + (c - 2)];
        f16 v2 = (c < 2) ? aggX[(size_t)n * 768 + t * 64 + b * 2 + c]
                         : uagg[(size_t)n * 2048 + b * 64 + (c - 2)];
        xg[b * RPAD + c] = v1;
        xg[b * RPAD + DPAD + c] = v2;
    }
    __syncthreads();

    f32x4 acc[2];
    acc[0] = (f32x4){0.f, 0.f, 0.f, 0.f};
    acc[1] = (f32x4){0.f, 0.f, 0.f, 0.f};
#pragma unroll
    for (int kk = 0; kk < KCH; kk++) {
        f16x8 av[2];
#pragma unroll
        for (int mt = 0; mt < 2; mt++)
            av[mt] = *(const f16x8*)&xg[(mt * 16 + lr) * RPAD + kk * 32 + lg * 8];
#pragma unroll
        for (int mt = 0; mt < 2; mt++)
            acc[mt] = __builtin_amdgcn_mfma_f32_16x16x32_f16(av[mt], wf[kk], acc[mt], 0, 0, 0);
    }
    float bias = 0.f;
#pragma unroll
    for (int e = 0; e < EE; e++) bias += emb[n * EE + e] * bpool[e * HH + o];
#pragma unroll
    for (int mt = 0; mt < 2; mt++)
#pragma unroll
        for (int q = 0; q < 4; q++) {
            int b = mt * 16 + lg * 4 + q;
            float v = acc[mt][q] + bias;
            float ex = __expf(2.f * v);
            float hc = 1.f - 2.f / (ex + 1.f);
            size_t hidx = ((size_t)n * 32 + b) * HH + o;
            float r = rbuf[hidx], h = hbuf[hidx];
            float hn = r * h + (1.f - r) * hc;
            hbuf[hidx] = hn;
            f16 hh = (f16)hn;
            h0rm[(size_t)n * 2048 + b * 64 + o] = hh;
            xs1[(size_t)n * 4096 + b * 128 + o] = hh;
            us1[(size_t)n * 4096 + b * 128 + o] = hh;
        }
}

// ---------------- gate1: zr = sigmoid([xs1 | aggH0,aggH1] @ Wg1 + b); us1 h-part = z*h1; r1 ------
__global__ __launch_bounds__(256) void k_gate1(const f16* __restrict__ xs1,
                                               const f16* __restrict__ aggA, const f16* __restrict__ aggB,
                                               const f16* __restrict__ WT, const float* __restrict__ bpool,
                                               const float* __restrict__ emb, const float* __restrict__ hbuf,
                                               f16* __restrict__ us1, float* __restrict__ rbuf) {
    constexpr int DPAD = 128, R = 256, RPAD = 264, KCH = 8, O = 128;
    int n = blockIdx.x;
    int tid = threadIdx.x, w = tid >> 6, l = tid & 63;
    int lr = l & 15, lg = l >> 4;
    __shared__ __align__(16) f16 xg[32 * RPAD];

    f16x8 wf[KCH][2];
    const f16* wbase = WT + (size_t)n * O * R;
#pragma unroll
    for (int kk = 0; kk < KCH; kk++)
#pragma unroll
        for (int nt = 0; nt < 2; nt++) {
            int o = w * 32 + nt * 16 + lr;
            wf[kk][nt] = *(const f16x8*)(wbase + (size_t)o * R + kk * 32 + lg * 8);
        }
    for (int e8 = tid; e8 < 32 * 16; e8 += 256) {
        int b = e8 >> 4, c8 = e8 & 15;
        *(f16x8*)&xg[b * RPAD + c8 * 8] = *(const f16x8*)&xs1[(size_t)n * 4096 + e8 * 8];
        f16x8 v = (c8 < 8) ? *(const f16x8*)&aggA[(size_t)n * 2048 + b * 64 + c8 * 8]
                           : *(const f16x8*)&aggB[(size_t)n * 2048 + b * 64 + (c8 - 8) * 8];
        *(f16x8*)&xg[b * RPAD + DPAD + c8 * 8] = v;
    }
    __syncthreads();

    f32x4 acc[2][2];
#pragma unroll
    for (int mt = 0; mt < 2; mt++)
#pragma unroll
        for (int nt = 0; nt < 2; nt++) acc[mt][nt] = (f32x4){0.f, 0.f, 0.f, 0.f};
#pragma unroll
    for (int kk = 0; kk < KCH; kk++) {
        f16x8 av[2];
#pragma unroll
        for (int mt = 0; mt < 2; mt++)
            av[mt] = *(const f16x8*)&xg[(mt * 16 + lr) * RPAD + kk * 32 + lg * 8];
#pragma unroll
        for (int mt = 0; mt < 2; mt++)
#pragma unroll
            for (int nt = 0; nt < 2; nt++)
                acc[mt][nt] = __builtin_amdgcn_mfma_f32_16x16x32_f16(av[mt], wf[kk][nt], acc[mt][nt], 0, 0, 0);
    }
#pragma unroll
    for (int mt = 0; mt < 2; mt++)
#pragma unroll
        for (int nt = 0; nt < 2; nt++) {
            int o = w * 32 + nt * 16 + lr;
            float bs = 0.f;
#pragma unroll
            for (int e = 0; e < EE; e++) bs += emb[n * EE + e] * bpool[e * 2 * HH + o];
#pragma unroll
            for (int q = 0; q < 4; q++) {
                int b = mt * 16 + lg * 4 + q;
                float v = acc[mt][nt][q] + bs;
                float sg = 1.f / (1.f + __expf(-v));
                if (o < HH) {
                    float u = sg * hbuf[((size_t)n * 32 + b) * HH + o];
                    us1[(size_t)n * 4096 + b * 128 + 64 + o] = (f16)u;
                } else {
                    rbuf[((size_t)n * 32 + b) * HH + (o - HH)] = sg;
                }
            }
        }
}

// ---------------- upd1: hc = tanh([us1 | aggH0,uagg1] @ Wu1 + b); h1' -> xs1 h-part, dout --------
__global__ __launch_bounds__(256) void k_upd1(const f16* __restrict__ us1,
                                              const f16* __restrict__ aggA, const f16* __restrict__ aggB,
                                              const f16* __restrict__ WT, const float* __restrict__ bpool,
                                              const float* __restrict__ emb,
                                              float* hbuf, const float* __restrict__ rbuf,
                                              f16* __restrict__ xs1, float* __restrict__ dout, int t) {
    constexpr int DPAD = 128, R = 256, RPAD = 264, KCH = 8, O = 64;
    int n = blockIdx.x;
    int tid = threadIdx.x, w = tid >> 6, l = tid & 63;
    int lr = l & 15, lg = l >> 4;
    __shared__ __align__(16) f16 xg[32 * RPAD];

    f16x8 wf[KCH];
    const f16* wbase = WT + (size_t)n * O * R;
    int o = w * 16 + lr;
#pragma unroll
    for (int kk = 0; kk < KCH; kk++)
        wf[kk] = *(const f16x8*)(wbase + (size_t)o * R + kk * 32 + lg * 8);

    for (int e8 = tid; e8 < 32 * 16; e8 += 256) {
        int b = e8 >> 4, c8 = e8 & 15;
        *(f16x8*)&xg[b * RPAD + c8 * 8] = *(const f16x8*)&us1[(size_t)n * 4096 + e8 * 8];
        f16x8 v = (c8 < 8) ? *(const f16x8*)&aggA[(size_t)n * 2048 + b * 64 + c8 * 8]
                           : *(const f16x8*)&aggB[(size_t)n * 2048 + b * 64 + (c8 - 8) * 8];
        *(f16x8*)&xg[b * RPAD + DPAD + c8 * 8] = v;
    }
    __syncthreads();

    f32x4 acc[2];
    acc[0] = (f32x4){0.f, 0.f, 0.f, 0.f};
    acc[1] = (f32x4){0.f, 0.f, 0.f, 0.f};
#pragma unroll
    for (int kk = 0; kk < KCH; kk++) {
        f16x8 av[2];
#pragma unroll
        for (int mt = 0; mt < 2; mt++)
            av[mt] = *(const f16x8*)&xg[(mt * 16 + lr) * RPAD + kk * 32 + lg * 8];
#pragma unroll
        for (int mt = 0; mt < 2; mt++)
            acc[mt] = __builtin_amdgcn_mfma_f32_16x16x32_f16(av[mt], wf[kk], acc[mt], 0, 0, 0);
    }
    float bias = 0.f;
#pragma unroll
    for (int e = 0; e < EE; e++) bias += emb[n * EE + e] * bpool[e * HH + o];
#pragma unroll
    for (int mt = 0; mt < 2; mt++)
#pragma unroll
        for (int q = 0; q < 4; q++) {
            int b = mt * 16 + lg * 4 + q;
            float v = acc[mt][q] + bias;
            float ex = __expf(2.f * v);
            float hc = 1.f - 2.f / (ex + 1.f);
            size_t hidx = ((size_t)n * 32 + b) * HH + o;
            float r = rbuf[hidx], h = hbuf[hidx];
            float hn = r * h + (1.f - r) * hc;
            hbuf[hidx] = hn;
            f16 hh = (f16)hn;
            xs1[(size_t)n * 4096 + b * 128 + 64 + o] = hh;
            dout[(((size_t)b * TT + t) * NN + n) * HH + o] = hn;
            if (t == TT - 1)
                dout[(size_t)BBATCH * TT * NN * HH + ((size_t)b * NN + n) * HH + o] = hn;
        }
}

extern "C" void kernel_launch(void* const* d_in, const int* in_sizes, int n_in,
                              void* d_out, int out_size, void* d_ws, size_t ws_size,
                              hipStream_t stream) {
    (void)in_sizes; (void)n_in; (void)out_size; (void)ws_size;
    const float* x   = (const float*)d_in[0];
    const float* emb = (const float*)d_in[1];
    const float* gw0 = (const float*)d_in[2];
    const float* gb0 = (const float*)d_in[3];
    const float* uw0 = (const float*)d_in[4];
    const float* ub0 = (const float*)d_in[5];
    const float* gw1 = (const float*)d_in[6];
    const float* gb1 = (const float*)d_in[7];
    const float* uw1 = (const float*)d_in[8];
    const float* ub1 = (const float*)d_in[9];
    float* out = (float*)d_out;

    char* p = (char*)d_ws;
    auto alloc = [&](size_t bytes) { char* r = p; p += (bytes + 255) & ~(size_t)255; return r; };
    f16* A2    = (f16*)alloc((size_t)NP * NP * 2);
    f16* Wg0   = (f16*)alloc((size_t)NN * 128 * 160 * 2);
    f16* Wu0   = (f16*)alloc((size_t)NN * 64 * 160 * 2);
    f16* Wg1   = (f16*)alloc((size_t)NN * 128 * 256 * 2);
    f16* Wu1   = (f16*)alloc((size_t)NN * 64 * 256 * 2);
    f16* xTall = (f16*)alloc((size_t)768 * NP * 2);
    f16* aggX  = (f16*)alloc((size_t)NP * 768 * 2);
    f16* h0rm  = (f16*)alloc((size_t)NN * 2048 * 2);
    f16* us0   = (f16*)alloc((size_t)NN * 2048 * 2);
    f16* usT0  = (f16*)alloc((size_t)2048 * NP * 2);
    f16* uagg0 = (f16*)alloc((size_t)NP * 2048 * 2);
    f16* aggH0 = (f16*)alloc((size_t)NP * 2048 * 2);
    f16* aggH1 = (f16*)alloc((size_t)NP * 2048 * 2);
    f16* xs1   = (f16*)alloc((size_t)NN * 4096 * 2);
    f16* xsT1  = (f16*)alloc((size_t)4096 * NP * 2);
    f16* us1   = (f16*)alloc((size_t)NN * 4096 * 2);
    f16* usT1  = (f16*)alloc((size_t)4096 * NP * 2);
    f16* uagg1 = (f16*)alloc((size_t)NP * 2048 * 2);
    float* h0  = (float*)alloc((size_t)NN * 32 * 64 * 4);
    float* r0  = (float*)alloc((size_t)NN * 32 * 64 * 4);
    float* h1  = (float*)alloc((size_t)NN * 32 * 64 * 4);
    float* r1  = (float*)alloc((size_t)NN * 32 * 64 * 4);

    // zero recurrent state: h-parts and their aggregations must be 0 at t=0
    hipMemsetAsync(h0rm, 0, (size_t)NN * 2048 * 2, stream);
    hipMemsetAsync(xs1, 0, (size_t)NN * 4096 * 2, stream);
    hipMemsetAsync(aggH0, 0, (size_t)NP * 2048 * 2, stream);
    hipMemsetAsync(aggH1, 0, (size_t)NP * 2048 * 2, stream);
    hipMemsetAsync(h0, 0, (size_t)NN * 32 * 64 * 4, stream);
    hipMemsetAsync(h1, 0, (size_t)NN * 32 * 64 * 4, stream);

    k_supports<<<NP, 256, 0, stream>>>(emb, A2);
    k_wgen<66, 128><<<NN / 4, 256, 0, stream>>>(emb, gw0, Wg0);
    k_wgen<66, 64><<<NN / 4, 256, 0, stream>>>(emb, uw0, Wu0);
    k_wgen<128, 128><<<NN / 4, 256, 0, stream>>>(emb, gw1, Wg1);
    k_wgen<128, 64><<<NN / 4, 256, 0, stream>>>(emb, uw1, Wu1);
    k_xall<<<768 * NP / 256, 256, 0, stream>>>(x, xTall);
    k_gemm<64, 0><<<dim3(12, 16), 256, 0, stream>>>(A2, xTall, aggX, 768);  // aggX = A @ x_all

    for (int t = 0; t < TT; t++) {
        // ---- layer 0 ----
        k_gate0<<<NN, 256, 0, stream>>>(x, t, h0rm, aggX, aggH0, Wg0, gb0, emb, h0, us0, r0);
        k_tr<2048, 1, 0><<<dim3(32, 32), 256, 0, stream>>>(us0, usT0);
        k_gemm<64, 0><<<dim3(32, 16), 256, 0, stream>>>(A2, usT0, uagg0, 2048);       // A@(z0*h0)
        k_upd0<<<NN, 256, 0, stream>>>(x, t, us0, aggX, uagg0, Wu0, ub0, emb, h0, r0,
                                       h0rm, xs1, us1);
        k_tr<4096, 2, 0><<<dim3(32, 32), 256, 0, stream>>>(xs1, xsT1);                // h0_t cols
        k_gemm<128, 0><<<dim3(32, 16), 256, 0, stream>>>(A2, xsT1, aggH0, 2048);      // A@h0_t
        // ---- layer 1 ----
        k_gate1<<<NN, 256, 0, stream>>>(xs1, aggH0, aggH1, Wg1, gb1, emb, h1, us1, r1);
        k_tr<4096, 2, 1><<<dim3(32, 32), 256, 0, stream>>>(us1, usT1);                // z1*h1 cols
        k_gemm<128, 64><<<dim3(32, 16), 256, 0, stream>>>(A2, usT1, uagg1, 2048);     // A@(z1*h1)
        k_upd1<<<NN, 256, 0, stream>>>(us1, aggH0, uagg1, Wu1, ub1, emb, h1, r1,
                                       xs1, out, t);
        k_tr<4096, 2, 1><<<dim3(32, 32), 256, 0, stream>>>(xs1, xsT1);                // h1_t cols
        k_gemm<128, 64><<<dim3(32, 16), 256, 0, stream>>>(A2, xsT1, aggH1, 2048);     // A@h1_t
    }
}

// Round 8
// 3903.711 us; speedup vs baseline: 1.2060x; 1.0338x over previous
//
#include <hip/hip_runtime.h>
#include <cstdint>

#define NN 2000     // nodes
#define NP 2048     // padded nodes
#define TT 12
#define BBATCH 32
#define HH 64
#define EE 10

typedef _Float16 f16;
typedef _Float16 f16x8 __attribute__((ext_vector_type(8)));
typedef float f32x4 __attribute__((ext_vector_type(4)));
typedef unsigned int u32;

// async global->LDS, 16B per lane; lds must be wave-uniform base (HW adds lane*16)
__device__ __forceinline__ void gld_lds16(const void* g, void* lds) {
    __builtin_amdgcn_global_load_lds(
        (const __attribute__((address_space(1))) u32*)(const void*)g,
        (__attribute__((address_space(3))) u32*)(void*)lds, 16, 0, 0);
}

// ---------------- supports: A = softmax(relu(emb @ emb^T)), fp16, padded [NP][NP] ----------------
__global__ __launch_bounds__(256) void k_supports(const float* __restrict__ emb, f16* __restrict__ A2) {
    int n = blockIdx.x;
    int tid = threadIdx.x;
    if (n >= NN) {
        for (int m = tid; m < NP; m += 256) A2[(size_t)n * NP + m] = (f16)0.f;
        return;
    }
    __shared__ float red[4];
    float en[EE];
#pragma unroll
    for (int e = 0; e < EE; e++) en[e] = emb[n * EE + e];
    float g[8];
    float mx = 0.f;
#pragma unroll
    for (int i = 0; i < 8; i++) {
        int m = tid + 256 * i;
        float v = 0.f;
        if (m < NN) {
            float a = 0.f;
#pragma unroll
            for (int e = 0; e < EE; e++) a += en[e] * emb[m * EE + e];
            v = fmaxf(a, 0.f);
            mx = fmaxf(mx, v);
        }
        g[i] = v;
    }
#pragma unroll
    for (int d = 32; d; d >>= 1) mx = fmaxf(mx, __shfl_xor(mx, d));
    if ((tid & 63) == 0) red[tid >> 6] = mx;
    __syncthreads();
    mx = fmaxf(fmaxf(red[0], red[1]), fmaxf(red[2], red[3]));
    float s = 0.f;
#pragma unroll
    for (int i = 0; i < 8; i++) {
        int m = tid + 256 * i;
        if (m < NN) { g[i] = __expf(g[i] - mx); s += g[i]; }
    }
#pragma unroll
    for (int d = 32; d; d >>= 1) s += __shfl_xor(s, d);
    __syncthreads();
    if ((tid & 63) == 0) red[tid >> 6] = s;
    __syncthreads();
    s = red[0] + red[1] + red[2] + red[3];
    float inv = 1.f / s;
#pragma unroll
    for (int i = 0; i < 8; i++) {
        int m = tid + 256 * i;
        A2[(size_t)n * NP + m] = (m < NN) ? (f16)(g[i] * inv) : (f16)0.f;
    }
}

// ---------------- wgen: W^T[n][o][r] = sum_e emb[n,e] * wpool[e,k(r),c(r),o]  (fp16) ----------------
template <int DIN, int O>
__global__ __launch_bounds__(256) void k_wgen(const float* __restrict__ emb,
                                              const float* __restrict__ wpool,
                                              f16* __restrict__ WT) {
    constexpr int DPAD = (DIN == 66) ? 80 : 128;
    constexpr int R = 2 * DPAD;
    int n0 = blockIdx.x * 4;
    int r = threadIdx.x;
    if (r >= R) return;
    int k = (r >= DPAD) ? 1 : 0;
    int c = r - k * DPAD;
    bool valid = (c < DIN);
    float en[4][EE];
#pragma unroll
    for (int j = 0; j < 4; j++)
#pragma unroll
        for (int e = 0; e < EE; e++) en[j][e] = emb[(n0 + j) * EE + e];
    const float* wp = wpool + ((size_t)(k * DIN + (valid ? c : 0))) * O;
    for (int o = 0; o < O; o += 4) {
        float4 a[4] = {};
        if (valid) {
#pragma unroll
            for (int e = 0; e < EE; e++) {
                float4 w4 = *(const float4*)(wp + (size_t)e * 2 * DIN * O + o);
#pragma unroll
                for (int j = 0; j < 4; j++) {
                    a[j].x += en[j][e] * w4.x; a[j].y += en[j][e] * w4.y;
                    a[j].z += en[j][e] * w4.z; a[j].w += en[j][e] * w4.w;
                }
            }
        }
#pragma unroll
        for (int j = 0; j < 4; j++) {
            f16* outp = WT + ((size_t)(n0 + j) * O + o) * R + r;
            outp[0] = (f16)a[j].x; outp[(size_t)R] = (f16)a[j].y;
            outp[(size_t)2 * R] = (f16)a[j].z; outp[(size_t)3 * R] = (f16)a[j].w;
        }
    }
}

// ---------------- xTall: [768][NP]; row r = t*64 + b*2 + d, col n = x[b][t][n][d] ----------------
__global__ __launch_bounds__(256) void k_xall(const float* __restrict__ x, f16* __restrict__ out) {
    int idx = blockIdx.x * 256 + threadIdx.x;
    if (idx >= 768 * NP) return;
    int r = idx >> 11, n = idx & (NP - 1);
    int t = r >> 6, rb = r & 63, b = rb >> 1, d = rb & 1;
    float v = (n < NN) ? x[(((size_t)b * TT + t) * NN + n) * 2 + d] : 0.f;
    out[idx] = (f16)v;
}

// ---------------- tiled transpose: out[(bx*TS+TO)*64+jl][m] = in[m][(bx*TS+TO)*64+jl] -------------
template <int W, int TS, int TO>
__global__ __launch_bounds__(256) void k_tr(const f16* __restrict__ in, f16* __restrict__ out) {
    __shared__ f16 t[64][72];
    int ebx = blockIdx.x * TS + TO, by = blockIdx.y;
    int tid = threadIdx.x;
    int ml = tid >> 2, q = tid & 3;
    int m = by * 64 + ml;
    f16x8 a, b2;
#pragma unroll
    for (int i = 0; i < 8; i++) { a[i] = (f16)0.f; b2[i] = (f16)0.f; }
    if (m < NN) {
        const f16* src = in + (size_t)m * W + ebx * 64 + q * 16;
        a = *(const f16x8*)src;
        b2 = *(const f16x8*)(src + 8);
    }
    *(f16x8*)&t[ml][q * 16] = a;
    *(f16x8*)&t[ml][q * 16 + 8] = b2;
    __syncthreads();
    int jl = tid >> 2;
    f16x8 r0, r1;
#pragma unroll
    for (int i = 0; i < 8; i++) r0[i] = t[q * 16 + i][jl];
#pragma unroll
    for (int i = 0; i < 8; i++) r1[i] = t[q * 16 + 8 + i][jl];
    f16* dst = out + (size_t)(ebx * 64 + jl) * NP + by * 64 + q * 16;
    *(f16x8*)dst = r0;
    *(f16x8*)(dst + 8) = r1;
}

// ---------------- aggregation GEMM (f16 out): C[2048][J] = A2 @ XT^T, 128x64 tile, BK=64 ---------
template <int ST, int OFF>
__global__ __launch_bounds__(256) void k_gemm(const f16* __restrict__ A2, const f16* __restrict__ XT,
                                              f16* __restrict__ C, int J) {
    __shared__ __align__(16) f16 at[128 * 64];
    __shared__ __align__(16) f16 xt[64 * 64];
    int tj = blockIdx.x * 64;
    int tm = blockIdx.y * 128;
    int rowbase = (tj >> 6) * ST + OFF;
    int tid = threadIdx.x;
    int w = tid >> 6, l = tid & 63;
    int lr = l & 15, lg = l >> 4;
    f32x4 acc[2][4];
#pragma unroll
    for (int mt = 0; mt < 2; mt++)
#pragma unroll
        for (int nt = 0; nt < 4; nt++) acc[mt][nt] = (f32x4){0.f, 0.f, 0.f, 0.f};

    for (int k0 = 0; k0 < 2048; k0 += 64) {
#pragma unroll
        for (int i = 0; i < 4; i++) {
            int e = w * 2048 + i * 512 + l * 8;
            int row = e >> 6, s = (e >> 3) & 7;
            const f16* src = A2 + (size_t)(tm + row) * 2048 + k0 + ((s ^ (row & 7)) << 3);
            gld_lds16(src, &at[w * 2048 + i * 512]);
        }
#pragma unroll
        for (int i = 0; i < 2; i++) {
            int e = w * 1024 + i * 512 + l * 8;
            int row = e >> 6, s = (e >> 3) & 7;
            const f16* src = XT + (size_t)(rowbase + row) * 2048 + k0 + ((s ^ (row & 7)) << 3);
            gld_lds16(src, &xt[w * 1024 + i * 512]);
        }
        __syncthreads();
#pragma unroll
        for (int kk = 0; kk < 2; kk++) {
            int s = kk * 4 + lg;
            f16x8 av[2], bv[4];
#pragma unroll
            for (int mt = 0; mt < 2; mt++) {
                int row = w * 32 + mt * 16 + lr;
                av[mt] = *(const f16x8*)&at[row * 64 + ((s ^ (row & 7)) << 3)];
            }
#pragma unroll
            for (int nt = 0; nt < 4; nt++) {
                int row = nt * 16 + lr;
                bv[nt] = *(const f16x8*)&xt[row * 64 + ((s ^ (row & 7)) << 3)];
            }
#pragma unroll
            for (int mt = 0; mt < 2; mt++)
#pragma unroll
                for (int nt = 0; nt < 4; nt++)
                    acc[mt][nt] = __builtin_amdgcn_mfma_f32_16x16x32_f16(av[mt], bv[nt], acc[mt][nt], 0, 0, 0);
        }
        __syncthreads();
    }
#pragma unroll
    for (int mt = 0; mt < 2; mt++)
#pragma unroll
        for (int nt = 0; nt < 4; nt++)
#pragma unroll
            for (int q = 0; q < 4; q++) {
                int row = tm + w * 32 + mt * 16 + lg * 4 + q;
                int col = tj + nt * 16 + lr;
                C[(size_t)row * J + col] = (f16)acc[mt][nt][q];
            }
}

// ---------------- split-K=2 GEMM (f32 partial out): P[kz][2048][2048], J=2048 --------------------
template <int ST, int OFF>
__global__ __launch_bounds__(256) void k_gemmk2(const f16* __restrict__ A2, const f16* __restrict__ XT,
                                                float* __restrict__ P) {
    __shared__ __align__(16) f16 at[128 * 64];
    __shared__ __align__(16) f16 xt[64 * 64];
    int tj = blockIdx.x * 64;
    int tm = blockIdx.y * 128;
    int kz = blockIdx.z;
    int rowbase = (tj >> 6) * ST + OFF;
    int tid = threadIdx.x;
    int w = tid >> 6, l = tid & 63;
    int lr = l & 15, lg = l >> 4;
    f32x4 acc[2][4];
#pragma unroll
    for (int mt = 0; mt < 2; mt++)
#pragma unroll
        for (int nt = 0; nt < 4; nt++) acc[mt][nt] = (f32x4){0.f, 0.f, 0.f, 0.f};

    for (int k0 = kz * 1024; k0 < kz * 1024 + 1024; k0 += 64) {
#pragma unroll
        for (int i = 0; i < 4; i++) {
            int e = w * 2048 + i * 512 + l * 8;
            int row = e >> 6, s = (e >> 3) & 7;
            const f16* src = A2 + (size_t)(tm + row) * 2048 + k0 + ((s ^ (row & 7)) << 3);
            gld_lds16(src, &at[w * 2048 + i * 512]);
        }
#pragma unroll
        for (int i = 0; i < 2; i++) {
            int e = w * 1024 + i * 512 + l * 8;
            int row = e >> 6, s = (e >> 3) & 7;
            const f16* src = XT + (size_t)(rowbase + row) * 2048 + k0 + ((s ^ (row & 7)) << 3);
            gld_lds16(src, &xt[w * 1024 + i * 512]);
        }
        __syncthreads();
#pragma unroll
        for (int kk = 0; kk < 2; kk++) {
            int s = kk * 4 + lg;
            f16x8 av[2], bv[4];
#pragma unroll
            for (int mt = 0; mt < 2; mt++) {
                int row = w * 32 + mt * 16 + lr;
                av[mt] = *(const f16x8*)&at[row * 64 + ((s ^ (row & 7)) << 3)];
            }
#pragma unroll
            for (int nt = 0; nt < 4; nt++) {
                int row = nt * 16 + lr;
                bv[nt] = *(const f16x8*)&xt[row * 64 + ((s ^ (row & 7)) << 3)];
            }
#pragma unroll
            for (int mt = 0; mt < 2; mt++)
#pragma unroll
                for (int nt = 0; nt < 4; nt++)
                    acc[mt][nt] = __builtin_amdgcn_mfma_f32_16x16x32_f16(av[mt], bv[nt], acc[mt][nt], 0, 0, 0);
        }
        __syncthreads();
    }
#pragma unroll
    for (int mt = 0; mt < 2; mt++)
#pragma unroll
        for (int nt = 0; nt < 4; nt++)
#pragma unroll
            for (int q = 0; q < 4; q++) {
                int row = tm + w * 32 + mt * 16 + lg * 4 + q;
                int col = tj + nt * 16 + lr;
                P[((size_t)kz * 2048 + row) * 2048 + col] = acc[mt][nt][q];
            }
}

// ---------------- gate0: zr = sigmoid([x_t,h0 | aggX,aggH01.h0] @ Wg0 + b); us0 = z*h0; r0 -------
__global__ __launch_bounds__(256) void k_gate0(const float* __restrict__ x, int t,
                                               const f16* __restrict__ h0rm, const f16* __restrict__ aggX,
                                               const f16* __restrict__ aggH01, const f16* __restrict__ WT,
                                               const float* __restrict__ bpool, const float* __restrict__ emb,
                                               const float* __restrict__ hbuf,
                                               f16* __restrict__ us_rm, float* __restrict__ rbuf) {
    constexpr int DIN = 66, DPAD = 80, RPAD = 168, KCH = 5, O = 128, R = 160;
    int n = blockIdx.x;
    int tid = threadIdx.x, w = tid >> 6, l = tid & 63;
    int lr = l & 15, lg = l >> 4;
    __shared__ __align__(16) f16 xg[32 * RPAD];

    f16x8 wf[KCH][2];
    const f16* wbase = WT + (size_t)n * O * R;
#pragma unroll
    for (int kk = 0; kk < KCH; kk++)
#pragma unroll
        for (int nt = 0; nt < 2; nt++) {
            int o = w * 32 + nt * 16 + lr;
            wf[kk][nt] = *(const f16x8*)(wbase + (size_t)o * R + kk * 32 + lg * 8);
        }
    for (int i = tid; i < 32 * RPAD / 8; i += 256) *(float4*)&xg[i * 8] = (float4){0.f, 0.f, 0.f, 0.f};
    __syncthreads();
    for (int e = tid; e < 32 * DIN; e += 256) {
        int b = e / DIN, c = e % DIN;
        f16 v1 = (c < 2) ? (f16)x[(((size_t)b * TT + t) * NN + n) * 2 + c]
                         : h0rm[(size_t)n * 2048 + b * 64 + (c - 2)];
        f16 v2 = (c < 2) ? aggX[(size_t)n * 768 + t * 64 + b * 2 + c]
                         : aggH01[(size_t)n * 4096 + b * 128 + (c - 2)];
        xg[b * RPAD + c] = v1;
        xg[b * RPAD + DPAD + c] = v2;
    }
    __syncthreads();

    f32x4 acc[2][2];
#pragma unroll
    for (int mt = 0; mt < 2; mt++)
#pragma unroll
        for (int nt = 0; nt < 2; nt++) acc[mt][nt] = (f32x4){0.f, 0.f, 0.f, 0.f};
#pragma unroll
    for (int kk = 0; kk < KCH; kk++) {
        f16x8 av[2];
#pragma unroll
        for (int mt = 0; mt < 2; mt++)
            av[mt] = *(const f16x8*)&xg[(mt * 16 + lr) * RPAD + kk * 32 + lg * 8];
#pragma unroll
        for (int mt = 0; mt < 2; mt++)
#pragma unroll
            for (int nt = 0; nt < 2; nt++)
                acc[mt][nt] = __builtin_amdgcn_mfma_f32_16x16x32_f16(av[mt], wf[kk][nt], acc[mt][nt], 0, 0, 0);
    }
#pragma unroll
    for (int mt = 0; mt < 2; mt++)
#pragma unroll
        for (int nt = 0; nt < 2; nt++) {
            int o = w * 32 + nt * 16 + lr;
            float bs = 0.f;
#pragma unroll
            for (int e = 0; e < EE; e++) bs += emb[n * EE + e] * bpool[e * 2 * HH + o];
#pragma unroll
            for (int q = 0; q < 4; q++) {
                int b = mt * 16 + lg * 4 + q;
                float v = acc[mt][nt][q] + bs;
                float sg = 1.f / (1.f + __expf(-v));
                if (o < HH) {
                    float u = sg * hbuf[((size_t)n * 32 + b) * HH + o];
                    us_rm[(size_t)n * 2048 + b * 64 + o] = (f16)u;
                } else {
                    rbuf[((size_t)n * 32 + b) * HH + (o - HH)] = sg;
                }
            }
        }
}

// ---------------- upd0: hc = tanh([x,z*h | aggX,(P0+P1)] @ Wu0 + b); h0' -> h0rm, xs1, us1 -------
__global__ __launch_bounds__(256) void k_upd0(const float* __restrict__ x, int t,
                                              const f16* __restrict__ us0, const f16* __restrict__ aggX,
                                              const float* __restrict__ P, const f16* __restrict__ WT,
                                              const float* __restrict__ bpool, const float* __restrict__ emb,
                                              float* hbuf, const float* __restrict__ rbuf,
                                              f16* __restrict__ h0rm, f16* __restrict__ xs1,
                                              f16* __restrict__ us1) {
    constexpr int DIN = 66, DPAD = 80, RPAD = 168, KCH = 5, O = 64, R = 160;
    int n = blockIdx.x;
    int tid = threadIdx.x, w = tid >> 6, l = tid & 63;
    int lr = l & 15, lg = l >> 4;
    __shared__ __align__(16) f16 xg[32 * RPAD];

    f16x8 wf[KCH];
    const f16* wbase = WT + (size_t)n * O * R;
    int o = w * 16 + lr;
#pragma unroll
    for (int kk = 0; kk < KCH; kk++)
        wf[kk] = *(const f16x8*)(wbase + (size_t)o * R + kk * 32 + lg * 8);

    for (int i = tid; i < 32 * RPAD / 8; i += 256) *(float4*)&xg[i * 8] = (float4){0.f, 0.f, 0.f, 0.f};
    __syncthreads();
    for (int e = tid; e < 32 * DIN; e += 256) {
        int b = e / DIN, c = e % DIN;
        f16 v1 = (c < 2) ? (f16)x[(((size_t)b * TT + t) * NN + n) * 2 + c]
                         : us0[(size_t)n * 2048 + b * 64 + (c - 2)];
        f16 v2;
        if (c < 2) {
            v2 = aggX[(size_t)n * 768 + t * 64 + b * 2 + c];
        } else {
            size_t idx = (size_t)n * 2048 + b * 64 + (c - 2);
            v2 = (f16)(P[idx] + P[(size_t)2048 * 2048 + idx]);
        }
        xg[b * RPAD + c] = v1;
        xg[b * RPAD + DPAD + c] = v2;
    }
    __syncthreads();

    f32x4 acc[2];
    acc[0] = (f32x4){0.f, 0.f, 0.f, 0.f};
    acc[1] = (f32x4){0.f, 0.f, 0.f, 0.f};
#pragma unroll
    for (int kk = 0; kk < KCH; kk++) {
        f16x8 av[2];
#pragma unroll
        for (int mt = 0; mt < 2; mt++)
            av[mt] = *(const f16x8*)&xg[(mt * 16 + lr) * RPAD + kk * 32 + lg * 8];
#pragma unroll
        for (int mt = 0; mt < 2; mt++)
            acc[mt] = __builtin_amdgcn_mfma_f32_16x16x32_f16(av[mt], wf[kk], acc[mt], 0, 0, 0);
    }
    float bias = 0.f;
#pragma unroll
    for (int e = 0; e < EE; e++) bias += emb[n * EE + e] * bpool[e * HH + o];
#pragma unroll
    for (int mt = 0; mt < 2; mt++)
#pragma unroll
        for (int q = 0; q < 4; q++) {
            int b = mt * 16 + lg * 4 + q;
            float v = acc[mt][q] + bias;
            float ex = __expf(2.f * v);
            float hc = 1.f - 2.f / (ex + 1.f);
            size_t hidx = ((size_t)n * 32 + b) * HH + o;
            float r = rbuf[hidx], h = hbuf[hidx];
            float hn = r * h + (1.f - r) * hc;
            hbuf[hidx] = hn;
            f16 hh = (f16)hn;
            h0rm[(size_t)n * 2048 + b * 64 + o] = hh;
            xs1[(size_t)n * 4096 + b * 128 + o] = hh;
            us1[(size_t)n * 4096 + b * 128 + o] = hh;
        }
}

// ---------------- gate1: zr = sigmoid([xs1 | aggH01] @ Wg1 + b); us1 h-part = z*h1; r1 -----------
__global__ __launch_bounds__(256) void k_gate1(const f16* __restrict__ xs1,
                                               const f16* __restrict__ aggH01,
                                               const f16* __restrict__ WT, const float* __restrict__ bpool,
                                               const float* __restrict__ emb, const float* __restrict__ hbuf,
                                               f16* __restrict__ us1, float* __restrict__ rbuf) {
    constexpr int DPAD = 128, RPAD = 264, KCH = 8, O = 128, R = 256;
    int n = blockIdx.x;
    int tid = threadIdx.x, w = tid >> 6, l = tid & 63;
    int lr = l & 15, lg = l >> 4;
    __shared__ __align__(16) f16 xg[32 * RPAD];

    f16x8 wf[KCH][2];
    const f16* wbase = WT + (size_t)n * O * R;
#pragma unroll
    for (int kk = 0; kk < KCH; kk++)
#pragma unroll
        for (int nt = 0; nt < 2; nt++) {
            int o = w * 32 + nt * 16 + lr;
            wf[kk][nt] = *(const f16x8*)(wbase + (size_t)o * R + kk * 32 + lg * 8);
        }
    for (int e8 = tid; e8 < 32 * 16; e8 += 256) {
        int b = e8 >> 4, c8 = e8 & 15;
        *(f16x8*)&xg[b * RPAD + c8 * 8] = *(const f16x8*)&xs1[(size_t)n * 4096 + e8 * 8];
        *(f16x8*)&xg[b * RPAD + DPAD + c8 * 8] = *(const f16x8*)&aggH01[(size_t)n * 4096 + e8 * 8];
    }
    __syncthreads();

    f32x4 acc[2][2];
#pragma unroll
    for (int mt = 0; mt < 2; mt++)
#pragma unroll
        for (int nt = 0; nt < 2; nt++) acc[mt][nt] = (f32x4){0.f, 0.f, 0.f, 0.f};
#pragma unroll
    for (int kk = 0; kk < KCH; kk++) {
        f16x8 av[2];
#pragma unroll
        for (int mt = 0; mt < 2; mt++)
            av[mt] = *(const f16x8*)&xg[(mt * 16 + lr) * RPAD + kk * 32 + lg * 8];
#pragma unroll
        for (int mt = 0; mt < 2; mt++)
#pragma unroll
            for (int nt = 0; nt < 2; nt++)
                acc[mt][nt] = __builtin_amdgcn_mfma_f32_16x16x32_f16(av[mt], wf[kk][nt], acc[mt][nt], 0, 0, 0);
    }
#pragma unroll
    for (int mt = 0; mt < 2; mt++)
#pragma unroll
        for (int nt = 0; nt < 2; nt++) {
            int o = w * 32 + nt * 16 + lr;
            float bs = 0.f;
#pragma unroll
            for (int e = 0; e < EE; e++) bs += emb[n * EE + e] * bpool[e * 2 * HH + o];
#pragma unroll
            for (int q = 0; q < 4; q++) {
                int b = mt * 16 + lg * 4 + q;
                float v = acc[mt][nt][q] + bs;
                float sg = 1.f / (1.f + __expf(-v));
                if (o < HH) {
                    float u = sg * hbuf[((size_t)n * 32 + b) * HH + o];
                    us1[(size_t)n * 4096 + b * 128 + 64 + o] = (f16)u;
                } else {
                    rbuf[((size_t)n * 32 + b) * HH + (o - HH)] = sg;
                }
            }
        }
}

// ---------------- upd1: hc = tanh([us1 | aggH01.h0,(P0+P1)] @ Wu1 + b); h1' -> xs1, dout ---------
__global__ __launch_bounds__(256) void k_upd1(const f16* __restrict__ us1,
                                              const f16* __restrict__ aggH01, const float* __restrict__ P,
                                              const f16* __restrict__ WT, const float* __restrict__ bpool,
                                              const float* __restrict__ emb,
                                              float* hbuf, const float* __restrict__ rbuf,
                                              f16* __restrict__ xs1, float* __restrict__ dout, int t) {
    constexpr int DPAD = 128, RPAD = 264, KCH = 8, O = 64, R = 256;
    int n = blockIdx.x;
    int tid = threadIdx.x, w = tid >> 6, l = tid & 63;
    int lr = l & 15, lg = l >> 4;
    __shared__ __align__(16) f16 xg[32 * RPAD];

    f16x8 wf[KCH];
    const f16* wbase = WT + (size_t)n * O * R;
    int o = w * 16 + lr;
#pragma unroll
    for (int kk = 0; kk < KCH; kk++)
        wf[kk] = *(const f16x8*)(wbase + (size_t)o * R + kk * 32 + lg * 8);

    for (int e8 = tid; e8 < 32 * 16; e8 += 256) {
        int b = e8 >> 4, c8 = e8 & 15;
        *(f16x8*)&xg[b * RPAD + c8 * 8] = *(const f16x8*)&us1[(size_t)n * 4096 + e8 * 8];
        f16x8 v;
        if (c8 < 8) {
            v = *(const f16x8*)&aggH01[(size_t)n * 4096 + b * 128 + c8 * 8];
        } else {
            size_t idx = (size_t)n * 2048 + b * 64 + (c8 - 8) * 8;
            float4 a0 = *(const float4*)&P[idx];
            float4 a1 = *(const float4*)&P[idx + 4];
            float4 b0 = *(const float4*)&P[(size_t)2048 * 2048 + idx];
            float4 b1 = *(const float4*)&P[(size_t)2048 * 2048 + idx + 4];
            v[0] = (f16)(a0.x + b0.x); v[1] = (f16)(a0.y + b0.y);
            v[2] = (f16)(a0.z + b0.z); v[3] = (f16)(a0.w + b0.w);
            v[4] = (f16)(a1.x + b1.x); v[5] = (f16)(a1.y + b1.y);
            v[6] = (f16)(a1.z + b1.z); v[7] = (f16)(a1.w + b1.w);
        }
        *(f16x8*)&xg[b * RPAD + DPAD + c8 * 8] = v;
    }
    __syncthreads();

    f32x4 acc[2];
    acc[0] = (f32x4){0.f, 0.f, 0.f, 0.f};
    acc[1] = (f32x4){0.f, 0.f, 0.f, 0.f};
#pragma unroll
    for (int kk = 0; kk < KCH; kk++) {
        f16x8 av[2];
#pragma unroll
        for (int mt = 0; mt < 2; mt++)
            av[mt] = *(const f16x8*)&xg[(mt * 16 + lr) * RPAD + kk * 32 + lg * 8];
#pragma unroll
        for (int mt = 0; mt < 2; mt++)
            acc[mt] = __builtin_amdgcn_mfma_f32_16x16x32_f16(av[mt], wf[kk], acc[mt], 0, 0, 0);
    }
    float bias = 0.f;
#pragma unroll
    for (int e = 0; e < EE; e++) bias += emb[n * EE + e] * bpool[e * HH + o];
#pragma unroll
    for (int mt = 0; mt < 2; mt++)
#pragma unroll
        for (int q = 0; q < 4; q++) {
            int b = mt * 16 + lg * 4 + q;
            float v = acc[mt][q] + bias;
            float ex = __expf(2.f * v);
            float hc = 1.f - 2.f / (ex + 1.f);
            size_t hidx = ((size_t)n * 32 + b) * HH + o;
            float r = rbuf[hidx], h = hbuf[hidx];
            float hn = r * h + (1.f - r) * hc;
            hbuf[hidx] = hn;
            f16 hh = (f16)hn;
            xs1[(size_t)n * 4096 + b * 128 + 64 + o] = hh;
            dout[(((size_t)b * TT + t) * NN + n) * HH + o] = hn;
            if (t == TT - 1)
                dout[(size_t)BBATCH * TT * NN * HH + ((size_t)b * NN + n) * HH + o] = hn;
        }
}

extern "C" void kernel_launch(void* const* d_in, const int* in_sizes, int n_in,
                              void* d_out, int out_size, void* d_ws, size_t ws_size,
                              hipStream_t stream) {
    (void)in_sizes; (void)n_in; (void)out_size; (void)ws_size;
    const float* x   = (const float*)d_in[0];
    const float* emb = (const float*)d_in[1];
    const float* gw0 = (const float*)d_in[2];
    const float* gb0 = (const float*)d_in[3];
    const float* uw0 = (const float*)d_in[4];
    const float* ub0 = (const float*)d_in[5];
    const float* gw1 = (const float*)d_in[6];
    const float* gb1 = (const float*)d_in[7];
    const float* uw1 = (const float*)d_in[8];
    const float* ub1 = (const float*)d_in[9];
    float* out = (float*)d_out;

    char* p = (char*)d_ws;
    auto alloc = [&](size_t bytes) { char* r = p; p += (bytes + 255) & ~(size_t)255; return r; };
    f16* A2     = (f16*)alloc((size_t)NP * NP * 2);
    f16* Wg0    = (f16*)alloc((size_t)NN * 128 * 160 * 2);
    f16* Wu0    = (f16*)alloc((size_t)NN * 64 * 160 * 2);
    f16* Wg1    = (f16*)alloc((size_t)NN * 128 * 256 * 2);
    f16* Wu1    = (f16*)alloc((size_t)NN * 64 * 256 * 2);
    f16* xTall  = (f16*)alloc((size_t)768 * NP * 2);
    f16* aggX   = (f16*)alloc((size_t)NP * 768 * 2);
    f16* h0rm   = (f16*)alloc((size_t)NN * 2048 * 2);
    f16* us0    = (f16*)alloc((size_t)NN * 2048 * 2);
    f16* usT0   = (f16*)alloc((size_t)2048 * NP * 2);
    float* Pbuf = (float*)alloc((size_t)2 * 2048 * 2048 * 4);
    f16* aggH01 = (f16*)alloc((size_t)NP * 4096 * 2);
    f16* xs1    = (f16*)alloc((size_t)NN * 4096 * 2);
    f16* xsT1   = (f16*)alloc((size_t)4096 * NP * 2);
    f16* us1    = (f16*)alloc((size_t)NN * 4096 * 2);
    f16* usT1   = (f16*)alloc((size_t)4096 * NP * 2);
    float* h0   = (float*)alloc((size_t)NN * 32 * 64 * 4);
    float* r0   = (float*)alloc((size_t)NN * 32 * 64 * 4);
    float* h1   = (float*)alloc((size_t)NN * 32 * 64 * 4);
    float* r1   = (float*)alloc((size_t)NN * 32 * 64 * 4);

    // zero recurrent state: h-parts and their aggregation must be 0 at t=0
    hipMemsetAsync(h0rm, 0, (size_t)NN * 2048 * 2, stream);
    hipMemsetAsync(xs1, 0, (size_t)NN * 4096 * 2, stream);
    hipMemsetAsync(aggH01, 0, (size_t)NP * 4096 * 2, stream);
    hipMemsetAsync(h0, 0, (size_t)NN * 32 * 64 * 4, stream);
    hipMemsetAsync(h1, 0, (size_t)NN * 32 * 64 * 4, stream);

    k_supports<<<NP, 256, 0, stream>>>(emb, A2);
    k_wgen<66, 128><<<NN / 4, 256, 0, stream>>>(emb, gw0, Wg0);
    k_wgen<66, 64><<<NN / 4, 256, 0, stream>>>(emb, uw0, Wu0);
    k_wgen<128, 128><<<NN / 4, 256, 0, stream>>>(emb, gw1, Wg1);
    k_wgen<128, 64><<<NN / 4, 256, 0, stream>>>(emb, uw1, Wu1);
    k_xall<<<768 * NP / 256, 256, 0, stream>>>(x, xTall);
    k_gemm<64, 0><<<dim3(12, 16), 256, 0, stream>>>(A2, xTall, aggX, 768);  // aggX = A @ x_all

    for (int t = 0; t < TT; t++) {
        // ---- layer 0 ----
        k_gate0<<<NN, 256, 0, stream>>>(x, t, h0rm, aggX, aggH01, Wg0, gb0, emb, h0, us0, r0);
        k_tr<2048, 1, 0><<<dim3(32, 32), 256, 0, stream>>>(us0, usT0);
        k_gemmk2<64, 0><<<dim3(32, 16, 2), 256, 0, stream>>>(A2, usT0, Pbuf);         // A@(z0*h0)
        k_upd0<<<NN, 256, 0, stream>>>(x, t, us0, aggX, Pbuf, Wu0, ub0, emb, h0, r0,
                                       h0rm, xs1, us1);
        k_tr<4096, 1, 0><<<dim3(64, 32), 256, 0, stream>>>(xs1, xsT1);                // [h0_t | h1_{t-1}]
        k_gemm<64, 0><<<dim3(64, 16), 256, 0, stream>>>(A2, xsT1, aggH01, 4096);      // A@[h0|h1]
        // ---- layer 1 ----
        k_gate1<<<NN, 256, 0, stream>>>(xs1, aggH01, Wg1, gb1, emb, h1, us1, r1);
        k_tr<4096, 2, 1><<<dim3(32, 32), 256, 0, stream>>>(us1, usT1);                // z1*h1 cols
        k_gemmk2<128, 64><<<dim3(32, 16, 2), 256, 0, stream>>>(A2, usT1, Pbuf);       // A@(z1*h1)
        k_upd1<<<NN, 256, 0, stream>>>(us1, aggH01, Pbuf, Wu1, ub1, emb, h1, r1,
                                       xs1, out, t);
    }
}